// Round 12
// baseline (1122.696 us; speedup 1.0000x reference)
//
#include <hip/hip_runtime.h>
#include <math.h>

// Problem constants (fixed shapes from setup_inputs)
#define Dn   12
#define Hn   448
#define Wn   224
#define HWn  (Hn*Wn)        // 100352
#define DHWn (Dn*HWn)       // 1204224
#define Cn   10

// Y1T layout is OCTET-BLOCKED per slice (c,d): element (L, h) stored at
//   (L>>3)*3584 + h*8 + (L&7)        (3584 = 448*8; octet = 28 KB contiguous)
// where L is the bit-rev-permuted line index (identity L = d7*32+l32).
// - colfft: one block per QUARTER-octet (2 lines, 128 thr); the 4 quarters of
//   an octet are 336 bids apart (= 0 mod 8) -> same XCD -> L2 merges segments.
// - rowfft stores / irow loads: per d7, 64-B segments; adjacent-row half-waves
//   complete each 128-B cache line -> no over-fetch.
#define OCT_F2 3584

// Twiddle table (float2 in global):
#define TW_W32   0     // 16:  W32^j
#define TW_W7    16    // 7:   W7^j (unused by Winograd path, kept for layout)
#define TW_W64   23    // 32:  W64^j
#define TW_T224  55    // 224: W224^{d7*l32}  [d7*32+l32]
#define TW_T448  279   // 448: W448^{d7*lane} [d7*64+lane]
#define TW_NT    727

// ---------- complex helpers ----------
__device__ __forceinline__ float2 cmul(float2 a, float2 b) {
    return make_float2(fmaf(a.x, b.x, -a.y * b.y), fmaf(a.x, b.y, a.y * b.x));
}
__device__ __forceinline__ float2 cfma(float2 a, float2 b, float2 acc) {
    acc.x = fmaf(a.x, b.x, fmaf(-a.y, b.y, acc.x));
    acc.y = fmaf(a.x, b.y, fmaf(a.y, b.x, acc.y));
    return acc;
}
__device__ __forceinline__ float2 cadd(float2 a, float2 b) { return make_float2(a.x + b.x, a.y + b.y); }
__device__ __forceinline__ float2 csub(float2 a, float2 b) { return make_float2(a.x - b.x, a.y - b.y); }
__host__ __device__ constexpr int brev5(int i) {
    return ((i & 1) << 4) | ((i & 2) << 2) | (i & 4) | ((i & 8) >> 2) | ((i & 16) >> 4);
}

__device__ __forceinline__ float2 shflx2(float2 v, int m) {
    return make_float2(__shfl_xor(v.x, m, 64), __shfl_xor(v.y, m, 64));
}

__device__ __forceinline__ double waveReduce(double v) {
#pragma unroll
    for (int o = 32; o > 0; o >>= 1) v += __shfl_down(v, o, 64);
    return v;
}

// ---------- Winograd-style DFT-7 (66 VALU ops vs 168 naive) ----------
// Forward (SGN=+1): y[k] = Sum_n x[n] exp(-2*pi*i*n*k/7) = A_k - i*B_k
// Inverse (SGN=-1): conj twiddles -> y[k] = A_k + i*B_k
template<int SGN>
__device__ __forceinline__ void dft7(const float2* __restrict__ x, float2* __restrict__ y) {
    const float c1 =  0.62348980185873359f;   // cos(2pi/7)
    const float c2 = -0.22252093395631445f;   // cos(4pi/7)
    const float c3 = -0.90096886790241915f;   // cos(6pi/7)
    const float s1 =  0.78183148246802980f;   // sin(2pi/7)
    const float s2 =  0.97492791218182362f;   // sin(4pi/7)
    const float s3 =  0.43388373911755823f;   // sin(6pi/7)
    float2 u1 = cadd(x[1], x[6]), v1 = csub(x[1], x[6]);
    float2 u2 = cadd(x[2], x[5]), v2 = csub(x[2], x[5]);
    float2 u3 = cadd(x[3], x[4]), v3 = csub(x[3], x[4]);
    y[0] = make_float2(x[0].x + u1.x + u2.x + u3.x,
                       x[0].y + u1.y + u2.y + u3.y);
    float2 A1, A2, A3, B1, B2, B3;
    A1.x = fmaf(c1, u1.x, fmaf(c2, u2.x, fmaf(c3, u3.x, x[0].x)));
    A1.y = fmaf(c1, u1.y, fmaf(c2, u2.y, fmaf(c3, u3.y, x[0].y)));
    A2.x = fmaf(c2, u1.x, fmaf(c3, u2.x, fmaf(c1, u3.x, x[0].x)));
    A2.y = fmaf(c2, u1.y, fmaf(c3, u2.y, fmaf(c1, u3.y, x[0].y)));
    A3.x = fmaf(c3, u1.x, fmaf(c1, u2.x, fmaf(c2, u3.x, x[0].x)));
    A3.y = fmaf(c3, u1.y, fmaf(c1, u2.y, fmaf(c2, u3.y, x[0].y)));
    B1.x = fmaf(s1, v1.x, fmaf(s2, v2.x,  s3 * v3.x));
    B1.y = fmaf(s1, v1.y, fmaf(s2, v2.y,  s3 * v3.y));
    B2.x = fmaf(s2, v1.x, fmaf(-s3, v2.x, -s1 * v3.x));
    B2.y = fmaf(s2, v1.y, fmaf(-s3, v2.y, -s1 * v3.y));
    B3.x = fmaf(s3, v1.x, fmaf(-s1, v2.x,  s2 * v3.x));
    B3.y = fmaf(s3, v1.y, fmaf(-s1, v2.y,  s2 * v3.y));
    if (SGN > 0) {
        y[1] = make_float2(A1.x + B1.y, A1.y - B1.x);
        y[6] = make_float2(A1.x - B1.y, A1.y + B1.x);
        y[2] = make_float2(A2.x + B2.y, A2.y - B2.x);
        y[5] = make_float2(A2.x - B2.y, A2.y + B2.x);
        y[3] = make_float2(A3.x + B3.y, A3.y - B3.x);
        y[4] = make_float2(A3.x - B3.y, A3.y + B3.x);
    } else {
        y[1] = make_float2(A1.x - B1.y, A1.y + B1.x);
        y[6] = make_float2(A1.x + B1.y, A1.y - B1.x);
        y[2] = make_float2(A2.x - B2.y, A2.y + B2.x);
        y[5] = make_float2(A2.x + B2.y, A2.y - B2.x);
        y[3] = make_float2(A3.x - B3.y, A3.y + B3.x);
        y[4] = make_float2(A3.x + B3.y, A3.y - B3.x);
    }
}

// ---------- init kernels ----------
__global__ void k_init_misc(float2* __restrict__ tws, double* __restrict__ S) {
    int t = threadIdx.x;  // 1024 threads
    const double PI2 = 6.283185307179586476925287;
    if (t < 16)              { double s, c; sincos(-(PI2 * t) / 32.0, &s, &c); tws[TW_W32 + t] = make_float2((float)c, (float)s); }
    if (t >= 16 && t < 23)   { int j = t - 16; double s, c; sincos(-(PI2 * j) / 7.0,  &s, &c); tws[TW_W7 + j]  = make_float2((float)c, (float)s); }
    if (t >= 23 && t < 55)   { int j = t - 23; double s, c; sincos(-(PI2 * j) / 64.0, &s, &c); tws[TW_W64 + j] = make_float2((float)c, (float)s); }
    if (t >= 55 && t < 279)  { int j = t - 55;  int d7 = j >> 5, l = j & 31;
                               double s, c; sincos(-(PI2 * (d7 * l)) / 224.0, &s, &c);
                               tws[TW_T224 + j] = make_float2((float)c, (float)s); }
    if (t >= 279 && t < 727) { int j = t - 279; int d7 = j >> 6, l = j & 63;
                               double s, c; sincos(-(PI2 * (d7 * l)) / 448.0, &s, &c);
                               tws[TW_T448 + j] = make_float2((float)c, (float)s); }
    if (t >= 727 && t < 759) S[t - 727] = 0.0;
}

__global__ void k_build_p(const float* __restrict__ z, const float* __restrict__ zf,
                          const float* __restrict__ miu,
                          float2* __restrict__ p, float2* __restrict__ r, float2* __restrict__ b,
                          double* __restrict__ S) {
    float mu = fabsf(miu[0]);
    double acc = 0.0;
    for (int e = blockIdx.x * blockDim.x + threadIdx.x; e < DHWn; e += gridDim.x * blockDim.x) {
        int d = e / HWn, rem = e - d * HWn;
        int h = rem / Wn, w = rem - h * Wn;
        int hs = h + Hn / 2; if (hs >= Hn) hs -= Hn;
        int ws = w + Wn / 2; if (ws >= Wn) ws -= Wn;
        int src = d * HWn + hs * Wn + ws;
        float pr = fmaf(mu, z[src], zf[src]);
        float pi = fmaf(mu, z[DHWn + src], zf[DHWn + src]);
        float2 v = make_float2(pr, pi);
        p[e] = v; r[e] = v; b[e] = make_float2(0.f, 0.f);
        acc += (double)pr * pr + (double)pi * pi;
    }
    acc = waveReduce(acc);
    if ((threadIdx.x & 63) == 0) atomicAdd(&S[0], acc);
}

__global__ void k_build_coil(const float* __restrict__ cr, const float* __restrict__ ci,
                             float2* __restrict__ coil) {
    for (int e = blockIdx.x * blockDim.x + threadIdx.x; e < Cn * HWn; e += gridDim.x * blockDim.x) {
        int c = e / HWn, rem = e - c * HWn;
        int h = rem / Wn, w = rem - h * Wn;
        int hs = h + Hn / 2; if (hs >= Hn) hs -= Hn;
        int ws = w + Wn / 2; if (ws >= Wn) ws -= Wn;
        int src = c * HWn + hs * Wn + ws;
        coil[e] = make_float2(cr[src], ci[src]);
    }
}

// permuted + shifted + scaled mask: maskP[L*448 + h], line L holds true
// frequency column w(L) = 7*brev5(L&31) + (L>>5)
__global__ void k_build_mask(const int* __restrict__ mask, float* __restrict__ maskP) {
    for (int e = blockIdx.x * blockDim.x + threadIdx.x; e < HWn; e += gridDim.x * blockDim.x) {
        int L = e / Hn, h = e - L * Hn;
        int w = 7 * brev5(L & 31) + (L >> 5);
        int hs = h + Hn / 2; if (hs >= Hn) hs -= Hn;
        int ws = w + Wn / 2; if (ws >= Wn) ws -= Wn;
        maskP[e] = (float)mask[hs * Wn + ws] * (1.0f / (float)HWn);
    }
}

// ---------- forward row FFT (224 = 7*32 lane-FFT), coil-mul, direct octet store ----------
// No LDS, no barriers. Per d7: lanes form 64-B segments; adjacent-row half-waves
// complete 128-B lines.
__global__ __launch_bounds__(256) void k_rowfft0(const float2* __restrict__ P,
                                                 const float2* __restrict__ coil,
                                                 float2* __restrict__ Y1T,
                                                 const float2* __restrict__ twg,
                                                 int chunkStart) {
    int tid = threadIdx.x;
    int lane = tid & 63, wv = tid >> 6, hi = lane >> 5, l32 = lane & 31;
    int h0 = blockIdx.x * 8, d = blockIdx.y, cz = blockIdx.z;
    int row = h0 + 2 * wv + hi;
    const float2* w32g = twg + TW_W32;
    const float2* t224 = twg + TW_T224;

    const float2* prow = P + (size_t)d * HWn + (size_t)row * Wn;
    const float2* crow = coil + (size_t)(chunkStart + cz) * HWn + (size_t)row * Wn;

    float2 xb[7];
#pragma unroll
    for (int b = 0; b < 7; ++b) xb[b] = cmul(prow[32 * b + l32], crow[32 * b + l32]);

    // DFT7 (Winograd)
    float2 y[7];
    dft7<1>(xb, y);
    // twiddle W224^{l32*d7} from table
#pragma unroll
    for (int d7 = 1; d7 < 7; ++d7) y[d7] = cmul(y[d7], t224[d7 * 32 + l32]);

    // FFT32 across each half-wave, DIF (sign-trick form: y' = (t + s*y)*weff)
#pragma unroll
    for (int s = 0; s < 5; ++s) {
        int dist = 16 >> s;
        float2 wst = w32g[(l32 & (dist - 1)) << s];
        bool h2 = (l32 & dist) != 0;
        float sg = h2 ? -1.f : 1.f;
        float2 weff = h2 ? wst : make_float2(1.f, 0.f);
#pragma unroll
        for (int d7 = 0; d7 < 7; ++d7) {
            float2 t = shflx2(y[d7], dist);
            float2 u = make_float2(fmaf(sg, y[d7].x, t.x), fmaf(sg, y[d7].y, t.y));
            y[d7] = cmul(u, weff);
        }
    }

    // direct store: line L = d7*32+l32 -> octet (L>>3), slot (L&7)
    float2* ybase = Y1T + ((size_t)cz * Dn + d) * (size_t)HWn;
    int oct0 = l32 >> 3, l8 = l32 & 7;
#pragma unroll
    for (int d7 = 0; d7 < 7; ++d7)
        ybase[(size_t)(4 * d7 + oct0) * OCT_F2 + (size_t)row * 8 + l8] = y[d7];
}

// ---------- column FFT448 + mask + IFFT448 ----------
// 128 threads = 2 waves; one block per QUARTER-octet (2 lines, 1 line/wave).
// LDS 7.2 KB -> 16 blocks/CU (wave-slot cap 32 waves = 100%); 13440 blocks
// (52/CU) for deep dispatch fill. gridDim.y = 48 encodes (d, quarter);
// sibling quarters differ by multiples of 336 bids (= 0 mod 8) -> same XCD ->
// L2 merges the interleaved 16-B segments.
#define CP 452
__global__ __launch_bounds__(128) void k_colfft(float2* __restrict__ Y1T,
                                                const float* __restrict__ maskP,
                                                const float2* __restrict__ twg) {
    __shared__ float2 ls[2][CP];
    int tid = threadIdx.x;               // 0..127
    int lane = tid & 63, wv = tid >> 6;  // 2 waves
    int oct = blockIdx.x;                // 28
    int byy = blockIdx.y;                // 48 = d + 12*quarter
    int quarter = byy / 12;
    int d = byy - 12 * quarter;
    int cz = blockIdx.z;
    const float2* w64t = twg + TW_W64;
    const float2* t448 = twg + TW_T448;

    float2* base = Y1T + ((size_t)cz * Dn + d) * (size_t)HWn + (size_t)oct * OCT_F2
                 + 2 * quarter;           // slots 2*quarter, 2*quarter+1

    // stage in: one f4 per h covers both slots (448 f4 total)
#pragma unroll
    for (int m = 0; m < 4; ++m) {
        int h = tid + m * 128;
        if (h < 448) {
            float4 v = *(const float4*)&base[(size_t)h * 8];
            ls[0][h] = make_float2(v.x, v.y);
            ls[1][h] = make_float2(v.z, v.w);
        }
    }
    __syncthreads();

    int L = oct * 8 + 2 * quarter + wv;   // this wave's line

    float2 xb[7];
#pragma unroll
    for (int b = 0; b < 7; ++b) xb[b] = ls[wv][64 * b + lane];

    // twiddles W448^{lane*d7} (reused conjugated in the inverse pass)
    float2 tp[7];
#pragma unroll
    for (int d7 = 1; d7 < 7; ++d7) tp[d7] = t448[d7 * 64 + lane];

    // forward DFT7 (Winograd) + W448 twiddle
    float2 y[7];
    dft7<1>(xb, y);
#pragma unroll
    for (int d7 = 1; d7 < 7; ++d7) y[d7] = cmul(y[d7], tp[d7]);

    // FFT64 across lanes, DIF (sign-trick): y' = (t + s*y) * weff
#pragma unroll
    for (int s = 0; s < 6; ++s) {
        int dist = 32 >> s;
        float2 wst = w64t[(lane & (dist - 1)) << s];
        bool hi = (lane & dist) != 0;
        float sg = hi ? -1.f : 1.f;
        float2 weff = hi ? wst : make_float2(1.f, 0.f);
#pragma unroll
        for (int d7 = 0; d7 < 7; ++d7) {
            float2 t = shflx2(y[d7], dist);
            float2 u = make_float2(fmaf(sg, y[d7].x, t.x), fmaf(sg, y[d7].y, t.y));
            y[d7] = cmul(u, weff);
        }
    }

    // mask: lane holds H-freq index 7*brev6(lane)+d7
    int rb = (brev5(lane & 31) << 1) | (lane >> 5);
    const float* mrow = maskP + (size_t)L * Hn + 7 * rb;
#pragma unroll
    for (int d7 = 0; d7 < 7; ++d7) {
        float m = mrow[d7];
        y[d7].x *= m; y[d7].y *= m;
    }

    // inverse FFT64, DIT (sign-trick): y' = A + c*B, c = +-conj(wst)
#pragma unroll
    for (int s = 0; s < 6; ++s) {
        int dist = 1 << s;
        float2 wst = w64t[(lane & (dist - 1)) << (5 - s)];
        wst.y = -wst.y;
        bool hi = (lane & dist) != 0;
        float2 c = hi ? make_float2(-wst.x, -wst.y) : wst;
#pragma unroll
        for (int d7 = 0; d7 < 7; ++d7) {
            float2 t = shflx2(y[d7], dist);
            float2 B = hi ? y[d7] : t;
            float2 A = hi ? t : y[d7];
            y[d7] = cfma(c, B, A);
        }
    }
    // conj W448 twiddle + inverse DFT7 (Winograd) + LDS writeback
#pragma unroll
    for (int d7 = 1; d7 < 7; ++d7) {
        float2 c = make_float2(tp[d7].x, -tp[d7].y);
        y[d7] = cmul(y[d7], c);
    }
    dft7<-1>(y, xb);
#pragma unroll
    for (int b = 0; b < 7; ++b) ls[wv][64 * b + lane] = xb[b];
    __syncthreads();

    // stage out: mirror of stage in
#pragma unroll
    for (int m = 0; m < 4; ++m) {
        int h = tid + m * 128;
        if (h < 448) {
            float2 a = ls[0][h];
            float2 b = ls[1][h];
            *(float4*)&base[(size_t)h * 8] = make_float4(a.x, a.y, b.x, b.y);
        }
    }
}

// ---------- fused inverse row FFT + conj-coil + coil-sum + q/dot epilogue ----------
// Octet layout: each half-wave loads its 7 DIT-ready line-groups directly into
// registers. NO LDS staging, NO barriers in the coil loop.
// Coil loop split over gridDim.z: z-chunk zid handles ccz coils, accumulating
// into partial Qp[zid]; dots are linear in q so each z-chunk adds its partial.
__global__ __launch_bounds__(256) void k_irow_combine(const float2* __restrict__ Y1T,
                                                      const float2* __restrict__ coil,
                                                      const float2* __restrict__ P,
                                                      float2* __restrict__ Qp,
                                                      const float* __restrict__ miu,
                                                      double* __restrict__ S,
                                                      const float2* __restrict__ twg,
                                                      int ccz, int chunkStart,
                                                      int first, int last, int it) {
    __shared__ double sred[8];
    int tid = threadIdx.x;
    int lane = tid & 63, wv = tid >> 6, hi = lane >> 5, l32 = lane & 31;
    int h0 = blockIdx.x * 8, d = blockIdx.y;
    int zid = blockIdx.z;
    int zbase = zid * ccz;
    float2* Q = Qp + (size_t)zid * DHWn;
    int row = h0 + 2 * wv + hi;
    const float2* w32g = twg + TW_W32;
    const float2* t224 = twg + TW_T224;

    float2 tp[7];
#pragma unroll
    for (int d7 = 1; d7 < 7; ++d7) {
        float2 v = t224[d7 * 32 + l32];
        tp[d7] = make_float2(v.x, -v.y);   // conj (inverse twiddle)
    }

    float2 acc[7];
#pragma unroll
    for (int b = 0; b < 7; ++b) acc[b] = make_float2(0.f, 0.f);

    int oct0 = l32 >> 3, l8 = l32 & 7;
    for (int cz = 0; cz < ccz; ++cz) {
        const float2* ybase = Y1T + ((size_t)(zbase + cz) * Dn + d) * (size_t)HWn;
        const float2* crow = coil + (size_t)(chunkStart + zbase + cz) * HWn + (size_t)row * Wn;

        // DIT-ready register loads: y[d7] = line (d7*32+l32) at this row
        float2 y[7];
#pragma unroll
        for (int d7 = 0; d7 < 7; ++d7)
            y[d7] = ybase[(size_t)(4 * d7 + oct0) * OCT_F2 + (size_t)row * 8 + l8];
        float2 cpre[7];
#pragma unroll
        for (int b = 0; b < 7; ++b) cpre[b] = crow[32 * b + l32];

        // inverse FFT32 across half-wave, DIT (sign-trick): y' = A + c*B
#pragma unroll
        for (int s = 0; s < 5; ++s) {
            int dist = 1 << s;
            float2 wst = w32g[(l32 & (dist - 1)) << (4 - s)];
            wst.y = -wst.y;
            bool h2 = (l32 & dist) != 0;
            float2 c = h2 ? make_float2(-wst.x, -wst.y) : wst;
#pragma unroll
            for (int d7 = 0; d7 < 7; ++d7) {
                float2 t = shflx2(y[d7], dist);
                float2 B = h2 ? y[d7] : t;
                float2 A = h2 ? t : y[d7];
                y[d7] = cfma(c, B, A);
            }
        }
        // conj twiddle W224^{-l32*d7}
#pragma unroll
        for (int d7 = 1; d7 < 7; ++d7) y[d7] = cmul(y[d7], tp[d7]);
        // inverse DFT7 (Winograd) + conj-coil accumulate
        float2 s7[7];
        dft7<-1>(y, s7);
#pragma unroll
        for (int b = 0; b < 7; ++b) {
            float2 s = s7[b];
            float2 c = cpre[b];
            acc[b].x += fmaf(s.x, c.x, s.y * c.y);
            acc[b].y += fmaf(s.y, c.x, -s.x * c.y);
        }
    }

    // epilogue: partial q; only zid==0 folds in mu*p (exactly once in the sum).
    float mu = fabsf(miu[0]);
    const float2* prow = P + (size_t)d * HWn + (size_t)row * Wn;
    float2* qrow = Q + (size_t)d * HWn + (size_t)row * Wn;
    double ar = 0.0, ai = 0.0;
#pragma unroll
    for (int b = 0; b < 7; ++b) {
        float2 pv = prow[32 * b + l32];
        float2 s0;
        if (first) {
            if (zid == 0) s0 = make_float2(fmaf(mu, pv.x, acc[b].x), fmaf(mu, pv.y, acc[b].y));
            else          s0 = acc[b];
        } else {
            float2 qv = qrow[32 * b + l32];
            s0 = cadd(qv, acc[b]);
        }
        qrow[32 * b + l32] = s0;
        if (last) {
            ar += (double)(s0.x * pv.x + s0.y * pv.y);
            ai += (double)(s0.y * pv.x - s0.x * pv.y);
        }
    }
    if (last) {
        ar = waveReduce(ar);
        ai = waveReduce(ai);
        if (lane == 0) { sred[wv] = ar; sred[4 + wv] = ai; }
        __syncthreads();
        if (tid == 0) {
            atomicAdd(&S[8 + it],  sred[0] + sred[1] + sred[2] + sred[3]);
            atomicAdd(&S[16 + it], sred[4] + sred[5] + sred[6] + sred[7]);
        }
    }
}

// ---------- CG scalar updates (float4 = 2 complex per lane) ----------
// q points at nz partial buffers, each N2 float4s; summed inline.
__global__ void k_update_br(const double* __restrict__ Sin, double* __restrict__ S, int it,
                            const float4* __restrict__ p, const float4* __restrict__ q,
                            int nz,
                            float4* __restrict__ b, float4* __restrict__ r) {
    double rr = Sin[it], qr = Sin[8 + it], qi = Sin[16 + it];
    double den = qr * qr + qi * qi;
    float arf = (float)(rr * qr / den);
    float aif = (float)(-rr * qi / den);
    double acc = 0.0;
    const int N2 = DHWn / 2;
    for (int e = blockIdx.x * blockDim.x + threadIdx.x; e < N2; e += gridDim.x * blockDim.x) {
        float4 pv = p[e], bv = b[e], rv = r[e];
        float4 qv = q[e];
        for (int z = 1; z < nz; ++z) {
            float4 t = q[(size_t)z * N2 + e];
            qv.x += t.x; qv.y += t.y; qv.z += t.z; qv.w += t.w;
        }
        bv.x += arf * pv.x - aif * pv.y;  bv.y += arf * pv.y + aif * pv.x;
        bv.z += arf * pv.z - aif * pv.w;  bv.w += arf * pv.w + aif * pv.z;
        b[e] = bv;
        rv.x -= arf * qv.x - aif * qv.y;  rv.y -= arf * qv.y + aif * qv.x;
        rv.z -= arf * qv.z - aif * qv.w;  rv.w -= arf * qv.w + aif * qv.z;
        r[e] = rv;
        acc += (double)rv.x * rv.x + (double)rv.y * rv.y
             + (double)rv.z * rv.z + (double)rv.w * rv.w;
    }
    acc = waveReduce(acc);
    if ((threadIdx.x & 63) == 0) atomicAdd(&S[it + 1], acc);
}

__global__ void k_update_p(const double* __restrict__ S, int it,
                           const float4* __restrict__ r, float4* __restrict__ p) {
    float beta = (float)(S[it + 1] / S[it]);
    const int N2 = DHWn / 2;
    for (int e = blockIdx.x * blockDim.x + threadIdx.x; e < N2; e += gridDim.x * blockDim.x) {
        float4 rv = r[e], pv = p[e];
        p[e] = make_float4(fmaf(beta, pv.x, rv.x), fmaf(beta, pv.y, rv.y),
                           fmaf(beta, pv.z, rv.z), fmaf(beta, pv.w, rv.w));
    }
}

__global__ void k_output(const float2* __restrict__ b, float* __restrict__ out) {
    for (int e = blockIdx.x * blockDim.x + threadIdx.x; e < DHWn; e += gridDim.x * blockDim.x) {
        int d = e / HWn, rem = e - d * HWn;
        int h = rem / Wn, w = rem - h * Wn;
        int hs = h + Hn / 2; if (hs >= Hn) hs -= Hn;
        int ws = w + Wn / 2; if (ws >= Wn) ws -= Wn;
        float2 v = b[d * HWn + hs * Wn + ws];
        out[e] = v.x;
        out[DHWn + e] = v.y;
    }
}

extern "C" void kernel_launch(void* const* d_in, const int* in_sizes, int n_in,
                              void* d_out, int out_size, void* d_ws, size_t ws_size,
                              hipStream_t stream) {
    const float* z      = (const float*)d_in[0];
    const float* zf     = (const float*)d_in[1];
    const float* coil_r = (const float*)d_in[2];
    const float* coil_i = (const float*)d_in[3];
    const int*   maskp  = (const int*)d_in[4];
    const float* miu    = (const float*)d_in[5];
    float* out = (float*)d_out;

    char* w = (char*)d_ws;
    size_t off = 0;
    auto carve = [&](size_t bytes) -> void* {
        void* ptr = w + off;
        off += (bytes + 511) & ~(size_t)511;
        return ptr;
    };
    float2* P     = (float2*)carve((size_t)DHWn * 8);
    float2* R     = (float2*)carve((size_t)DHWn * 8);
    float2* Bv    = (float2*)carve((size_t)DHWn * 8);
    float2* COIL  = (float2*)carve((size_t)Cn * HWn * 8);
    float*  MASKP = (float*)carve((size_t)HWn * 4);
    float2* TWS   = (float2*)carve(TW_NT * 8);
    double* S     = (double*)carve(64 * 8);

    size_t imgSet = (size_t)DHWn * 8;   // one coil-slot (12 slices), 9.63 MB
    // (coils staged per chunk, z-splits of the combine); NZ divides cc.
    int cc = 1, NZ = 1;
    {
        const int cand[6][2] = {{10,2},{10,1},{5,1},{2,1},{1,1},{1,1}};
        for (int i = 0; i < 6; ++i) {
            size_t need = off + (size_t)(cand[i][0] + cand[i][1]) * imgSet;
            if (need <= ws_size) { cc = cand[i][0]; NZ = cand[i][1]; break; }
        }
    }
    float2* Qp  = (float2*)carve((size_t)NZ * imgSet);   // NZ partial-q buffers
    float2* Y1T = (float2*)carve((size_t)cc * imgSet);   // staged slices [c][d][oct][h][l8]
    int nch = Cn / cc;
    int ccz = cc / NZ;

    k_init_misc<<<1, 1024, 0, stream>>>(TWS, S);
    k_build_p<<<1024, 256, 0, stream>>>(z, zf, miu, P, R, Bv, S);
    k_build_coil<<<1024, 256, 0, stream>>>(coil_r, coil_i, COIL);
    k_build_mask<<<512, 256, 0, stream>>>(maskp, MASKP);

    for (int it = 0; it < 5; ++it) {
        for (int ch = 0; ch < nch; ++ch) {
            int cs = ch * cc;
            dim3 gf(Hn / 8, Dn, cc);    // 56 x 12 x cc
            dim3 gc(28, 48, cc);        // octet x (d + 12*quarter) x cc
            dim3 gi(Hn / 8, Dn, NZ);    // 56 x 12 x NZ, each z does cc/NZ coils
            k_rowfft0<<<gf, 256, 0, stream>>>(P, COIL, Y1T, TWS, cs);
            k_colfft<<<gc, 128, 0, stream>>>(Y1T, MASKP, TWS);
            k_irow_combine<<<gi, 256, 0, stream>>>(Y1T, COIL, P, Qp, miu, S, TWS,
                                                   ccz, cs, ch == 0 ? 1 : 0,
                                                   ch == nch - 1 ? 1 : 0, it);
        }
        k_update_br<<<1024, 256, 0, stream>>>(S, S, it, (const float4*)P, (const float4*)Qp,
                                              NZ, (float4*)Bv, (float4*)R);
        if (it < 4) k_update_p<<<1024, 256, 0, stream>>>(S, it, (const float4*)R, (float4*)P);
    }
    k_output<<<1024, 256, 0, stream>>>(Bv, out);
}

// Round 13
// 1098.782 us; speedup vs baseline: 1.0218x; 1.0218x over previous
//
#include <hip/hip_runtime.h>
#include <math.h>

// Problem constants (fixed shapes from setup_inputs)
#define Dn   12
#define Hn   448
#define Wn   224
#define HWn  (Hn*Wn)        // 100352
#define DHWn (Dn*HWn)       // 1204224
#define Cn   10

// Y1T layout is OCTET-BLOCKED per slice (c,d): element (L, h) stored at
//   (L>>3)*3584 + h*8 + (L&7)        (3584 = 448*8; octet = 28 KB contiguous)
// where L is the bit-rev-permuted line index (identity L = d7*32+l32).
// - colfft: one block per HALF-octet (4 lines); the two halves of an octet are
//   placed 336 bids apart (= 0 mod 8) so they land on the SAME XCD and share L2.
// - rowfft stores / irow loads: per d7, 64-B segments; adjacent-row half-waves
//   complete each 128-B cache line -> no over-fetch.
#define OCT_F2 3584

// Twiddle table (float2 in global):
#define TW_W32   0     // 16:  W32^j
#define TW_W7    16    // 7:   W7^j (unused by Winograd path, kept for layout)
#define TW_W64   23    // 32:  W64^j
#define TW_T224  55    // 224: W224^{d7*l32}  [d7*32+l32]
#define TW_T448  279   // 448: W448^{d7*lane} [d7*64+lane]
#define TW_NT    727

// ---------- complex helpers ----------
__device__ __forceinline__ float2 cmul(float2 a, float2 b) {
    return make_float2(fmaf(a.x, b.x, -a.y * b.y), fmaf(a.x, b.y, a.y * b.x));
}
__device__ __forceinline__ float2 cfma(float2 a, float2 b, float2 acc) {
    acc.x = fmaf(a.x, b.x, fmaf(-a.y, b.y, acc.x));
    acc.y = fmaf(a.x, b.y, fmaf(a.y, b.x, acc.y));
    return acc;
}
__device__ __forceinline__ float2 cadd(float2 a, float2 b) { return make_float2(a.x + b.x, a.y + b.y); }
__device__ __forceinline__ float2 csub(float2 a, float2 b) { return make_float2(a.x - b.x, a.y - b.y); }
__host__ __device__ constexpr int brev5(int i) {
    return ((i & 1) << 4) | ((i & 2) << 2) | (i & 4) | ((i & 8) >> 2) | ((i & 16) >> 4);
}

__device__ __forceinline__ float2 shflx2(float2 v, int m) {
    return make_float2(__shfl_xor(v.x, m, 64), __shfl_xor(v.y, m, 64));
}

__device__ __forceinline__ double waveReduce(double v) {
#pragma unroll
    for (int o = 32; o > 0; o >>= 1) v += __shfl_down(v, o, 64);
    return v;
}

// ---------- Winograd-style DFT-7 (66 VALU ops vs 168 naive) ----------
// Forward (SGN=+1): y[k] = Sum_n x[n] exp(-2*pi*i*n*k/7) = A_k - i*B_k
// Inverse (SGN=-1): conj twiddles -> y[k] = A_k + i*B_k
template<int SGN>
__device__ __forceinline__ void dft7(const float2* __restrict__ x, float2* __restrict__ y) {
    const float c1 =  0.62348980185873359f;   // cos(2pi/7)
    const float c2 = -0.22252093395631445f;   // cos(4pi/7)
    const float c3 = -0.90096886790241915f;   // cos(6pi/7)
    const float s1 =  0.78183148246802980f;   // sin(2pi/7)
    const float s2 =  0.97492791218182362f;   // sin(4pi/7)
    const float s3 =  0.43388373911755823f;   // sin(6pi/7)
    float2 u1 = cadd(x[1], x[6]), v1 = csub(x[1], x[6]);
    float2 u2 = cadd(x[2], x[5]), v2 = csub(x[2], x[5]);
    float2 u3 = cadd(x[3], x[4]), v3 = csub(x[3], x[4]);
    y[0] = make_float2(x[0].x + u1.x + u2.x + u3.x,
                       x[0].y + u1.y + u2.y + u3.y);
    float2 A1, A2, A3, B1, B2, B3;
    A1.x = fmaf(c1, u1.x, fmaf(c2, u2.x, fmaf(c3, u3.x, x[0].x)));
    A1.y = fmaf(c1, u1.y, fmaf(c2, u2.y, fmaf(c3, u3.y, x[0].y)));
    A2.x = fmaf(c2, u1.x, fmaf(c3, u2.x, fmaf(c1, u3.x, x[0].x)));
    A2.y = fmaf(c2, u1.y, fmaf(c3, u2.y, fmaf(c1, u3.y, x[0].y)));
    A3.x = fmaf(c3, u1.x, fmaf(c1, u2.x, fmaf(c2, u3.x, x[0].x)));
    A3.y = fmaf(c3, u1.y, fmaf(c1, u2.y, fmaf(c2, u3.y, x[0].y)));
    B1.x = fmaf(s1, v1.x, fmaf(s2, v2.x,  s3 * v3.x));
    B1.y = fmaf(s1, v1.y, fmaf(s2, v2.y,  s3 * v3.y));
    B2.x = fmaf(s2, v1.x, fmaf(-s3, v2.x, -s1 * v3.x));
    B2.y = fmaf(s2, v1.y, fmaf(-s3, v2.y, -s1 * v3.y));
    B3.x = fmaf(s3, v1.x, fmaf(-s1, v2.x,  s2 * v3.x));
    B3.y = fmaf(s3, v1.y, fmaf(-s1, v2.y,  s2 * v3.y));
    if (SGN > 0) {
        y[1] = make_float2(A1.x + B1.y, A1.y - B1.x);
        y[6] = make_float2(A1.x - B1.y, A1.y + B1.x);
        y[2] = make_float2(A2.x + B2.y, A2.y - B2.x);
        y[5] = make_float2(A2.x - B2.y, A2.y + B2.x);
        y[3] = make_float2(A3.x + B3.y, A3.y - B3.x);
        y[4] = make_float2(A3.x - B3.y, A3.y + B3.x);
    } else {
        y[1] = make_float2(A1.x - B1.y, A1.y + B1.x);
        y[6] = make_float2(A1.x + B1.y, A1.y - B1.x);
        y[2] = make_float2(A2.x - B2.y, A2.y + B2.x);
        y[5] = make_float2(A2.x + B2.y, A2.y - B2.x);
        y[3] = make_float2(A3.x - B3.y, A3.y + B3.x);
        y[4] = make_float2(A3.x + B3.y, A3.y - B3.x);
    }
}

// ---------- init kernels ----------
__global__ void k_init_misc(float2* __restrict__ tws, double* __restrict__ S) {
    int t = threadIdx.x;  // 1024 threads
    const double PI2 = 6.283185307179586476925287;
    if (t < 16)              { double s, c; sincos(-(PI2 * t) / 32.0, &s, &c); tws[TW_W32 + t] = make_float2((float)c, (float)s); }
    if (t >= 16 && t < 23)   { int j = t - 16; double s, c; sincos(-(PI2 * j) / 7.0,  &s, &c); tws[TW_W7 + j]  = make_float2((float)c, (float)s); }
    if (t >= 23 && t < 55)   { int j = t - 23; double s, c; sincos(-(PI2 * j) / 64.0, &s, &c); tws[TW_W64 + j] = make_float2((float)c, (float)s); }
    if (t >= 55 && t < 279)  { int j = t - 55;  int d7 = j >> 5, l = j & 31;
                               double s, c; sincos(-(PI2 * (d7 * l)) / 224.0, &s, &c);
                               tws[TW_T224 + j] = make_float2((float)c, (float)s); }
    if (t >= 279 && t < 727) { int j = t - 279; int d7 = j >> 6, l = j & 63;
                               double s, c; sincos(-(PI2 * (d7 * l)) / 448.0, &s, &c);
                               tws[TW_T448 + j] = make_float2((float)c, (float)s); }
    if (t >= 727 && t < 759) S[t - 727] = 0.0;
}

__global__ void k_build_p(const float* __restrict__ z, const float* __restrict__ zf,
                          const float* __restrict__ miu,
                          float2* __restrict__ p, float2* __restrict__ r, float2* __restrict__ b,
                          double* __restrict__ S) {
    float mu = fabsf(miu[0]);
    double acc = 0.0;
    for (int e = blockIdx.x * blockDim.x + threadIdx.x; e < DHWn; e += gridDim.x * blockDim.x) {
        int d = e / HWn, rem = e - d * HWn;
        int h = rem / Wn, w = rem - h * Wn;
        int hs = h + Hn / 2; if (hs >= Hn) hs -= Hn;
        int ws = w + Wn / 2; if (ws >= Wn) ws -= Wn;
        int src = d * HWn + hs * Wn + ws;
        float pr = fmaf(mu, z[src], zf[src]);
        float pi = fmaf(mu, z[DHWn + src], zf[DHWn + src]);
        float2 v = make_float2(pr, pi);
        p[e] = v; r[e] = v; b[e] = make_float2(0.f, 0.f);
        acc += (double)pr * pr + (double)pi * pi;
    }
    acc = waveReduce(acc);
    if ((threadIdx.x & 63) == 0) atomicAdd(&S[0], acc);
}

__global__ void k_build_coil(const float* __restrict__ cr, const float* __restrict__ ci,
                             float2* __restrict__ coil) {
    for (int e = blockIdx.x * blockDim.x + threadIdx.x; e < Cn * HWn; e += gridDim.x * blockDim.x) {
        int c = e / HWn, rem = e - c * HWn;
        int h = rem / Wn, w = rem - h * Wn;
        int hs = h + Hn / 2; if (hs >= Hn) hs -= Hn;
        int ws = w + Wn / 2; if (ws >= Wn) ws -= Wn;
        int src = c * HWn + hs * Wn + ws;
        coil[e] = make_float2(cr[src], ci[src]);
    }
}

// permuted + shifted + scaled mask: maskP[L*448 + h], line L holds true
// frequency column w(L) = 7*brev5(L&31) + (L>>5)
__global__ void k_build_mask(const int* __restrict__ mask, float* __restrict__ maskP) {
    for (int e = blockIdx.x * blockDim.x + threadIdx.x; e < HWn; e += gridDim.x * blockDim.x) {
        int L = e / Hn, h = e - L * Hn;
        int w = 7 * brev5(L & 31) + (L >> 5);
        int hs = h + Hn / 2; if (hs >= Hn) hs -= Hn;
        int ws = w + Wn / 2; if (ws >= Wn) ws -= Wn;
        maskP[e] = (float)mask[hs * Wn + ws] * (1.0f / (float)HWn);
    }
}

// ---------- forward row FFT (224 = 7*32 lane-FFT), coil-mul, direct octet store ----------
// No LDS, no barriers. Per d7: lanes form 64-B segments; adjacent-row half-waves
// complete 128-B lines.
// FUSED update_p: for it>=1, p = r + beta*p_old computed on the fly
// (beta = S[it]/S[it-1], identical arithmetic to the old k_update_p);
// the global-coil-0 block stores p into Pnew (ping-pong, no races).
__global__ __launch_bounds__(256) void k_rowfft0(const float2* __restrict__ Pread,
                                                 const float2* __restrict__ Rv,
                                                 float2* __restrict__ Pnew,
                                                 const float2* __restrict__ coil,
                                                 float2* __restrict__ Y1T,
                                                 const float2* __restrict__ twg,
                                                 const double* __restrict__ S,
                                                 int chunkStart, int it) {
    int tid = threadIdx.x;
    int lane = tid & 63, wv = tid >> 6, hi = lane >> 5, l32 = lane & 31;
    int h0 = blockIdx.x * 8, d = blockIdx.y, cz = blockIdx.z;
    int row = h0 + 2 * wv + hi;
    const float2* w32g = twg + TW_W32;
    const float2* t224 = twg + TW_T224;

    size_t roff = (size_t)d * HWn + (size_t)row * Wn;
    const float2* prow = Pread + roff;
    const float2* crow = coil + (size_t)(chunkStart + cz) * HWn + (size_t)row * Wn;

    float2 pv[7];
    if (it == 0) {
#pragma unroll
        for (int b = 0; b < 7; ++b) pv[b] = prow[32 * b + l32];
    } else {
        float beta = (float)(S[it] / S[it - 1]);
        const float2* rrow = Rv + roff;
#pragma unroll
        for (int b = 0; b < 7; ++b) {
            float2 rv = rrow[32 * b + l32];
            float2 po = prow[32 * b + l32];
            pv[b] = make_float2(fmaf(beta, po.x, rv.x), fmaf(beta, po.y, rv.y));
        }
        if (chunkStart + cz == 0) {
            float2* pw = Pnew + roff;
#pragma unroll
            for (int b = 0; b < 7; ++b) pw[32 * b + l32] = pv[b];
        }
    }

    float2 xb[7];
#pragma unroll
    for (int b = 0; b < 7; ++b) xb[b] = cmul(pv[b], crow[32 * b + l32]);

    // DFT7 (Winograd)
    float2 y[7];
    dft7<1>(xb, y);
    // twiddle W224^{l32*d7} from table
#pragma unroll
    for (int d7 = 1; d7 < 7; ++d7) y[d7] = cmul(y[d7], t224[d7 * 32 + l32]);

    // FFT32 across each half-wave, DIF (sign-trick form: y' = (t + s*y)*weff)
#pragma unroll
    for (int s = 0; s < 5; ++s) {
        int dist = 16 >> s;
        float2 wst = w32g[(l32 & (dist - 1)) << s];
        bool h2 = (l32 & dist) != 0;
        float sg = h2 ? -1.f : 1.f;
        float2 weff = h2 ? wst : make_float2(1.f, 0.f);
#pragma unroll
        for (int d7 = 0; d7 < 7; ++d7) {
            float2 t = shflx2(y[d7], dist);
            float2 u = make_float2(fmaf(sg, y[d7].x, t.x), fmaf(sg, y[d7].y, t.y));
            y[d7] = cmul(u, weff);
        }
    }

    // direct store: line L = d7*32+l32 -> octet (L>>3), slot (L&7)
    float2* ybase = Y1T + ((size_t)cz * Dn + d) * (size_t)HWn;
    int oct0 = l32 >> 3, l8 = l32 & 7;
#pragma unroll
    for (int d7 = 0; d7 < 7; ++d7)
        ybase[(size_t)(4 * d7 + oct0) * OCT_F2 + (size_t)row * 8 + l8] = y[d7];
}

// ---------- column FFT448 + mask + IFFT448 ----------
// 256 threads = 4 waves; one block per HALF-octet (4 lines, 1 line/wave).
// LDS 14.5 KB -> 8 blocks/CU wave-slot cap. gridDim.y = 24 encodes (d, half);
// sibling halves differ by 28*12=336 bids (multiple of 8) -> same XCD -> L2
// merges the interleaved 32-B reads.
#define CP 452
__global__ __launch_bounds__(256) void k_colfft(float2* __restrict__ Y1T,
                                                const float* __restrict__ maskP,
                                                const float2* __restrict__ twg) {
    __shared__ float2 ls[4][CP];
    int tid = threadIdx.x;               // 0..255
    int lane = tid & 63, wv = tid >> 6;  // 4 waves
    int oct = blockIdx.x;                // 28
    int byy = blockIdx.y;                // 24 = d + 12*half
    int d = (byy < 12) ? byy : byy - 12;
    int half = (byy < 12) ? 0 : 1;
    int cz = blockIdx.z;
    const float2* w64t = twg + TW_W64;
    const float2* t448 = twg + TW_T448;

    float2* base = Y1T + ((size_t)cz * Dn + d) * (size_t)HWn + (size_t)oct * OCT_F2
                 + 4 * half;             // slots 4*half .. 4*half+3

    // stage in: 448 h x 4 slots = 1792 f2 = 896 f4 (two f4 per h)
#pragma unroll
    for (int m = 0; m < 4; ++m) {
        int j4 = tid + m * 256;
        if (j4 < 896) {
            int h = j4 >> 1, q = j4 & 1;     // f4 covers local slots 2q, 2q+1 at col h
            float4 v = *(const float4*)&base[(size_t)h * 8 + 2 * q];
            ls[2 * q][h]     = make_float2(v.x, v.y);
            ls[2 * q + 1][h] = make_float2(v.z, v.w);
        }
    }
    __syncthreads();

    int L = oct * 8 + 4 * half + wv;     // this wave's line

    float2 xb[7];
#pragma unroll
    for (int b = 0; b < 7; ++b) xb[b] = ls[wv][64 * b + lane];

    // twiddles W448^{lane*d7} (reused conjugated in the inverse pass)
    float2 tp[7];
#pragma unroll
    for (int d7 = 1; d7 < 7; ++d7) tp[d7] = t448[d7 * 64 + lane];

    // forward DFT7 (Winograd) + W448 twiddle
    float2 y[7];
    dft7<1>(xb, y);
#pragma unroll
    for (int d7 = 1; d7 < 7; ++d7) y[d7] = cmul(y[d7], tp[d7]);

    // FFT64 across lanes, DIF (sign-trick): y' = (t + s*y) * weff
#pragma unroll
    for (int s = 0; s < 6; ++s) {
        int dist = 32 >> s;
        float2 wst = w64t[(lane & (dist - 1)) << s];
        bool hi = (lane & dist) != 0;
        float sg = hi ? -1.f : 1.f;
        float2 weff = hi ? wst : make_float2(1.f, 0.f);
#pragma unroll
        for (int d7 = 0; d7 < 7; ++d7) {
            float2 t = shflx2(y[d7], dist);
            float2 u = make_float2(fmaf(sg, y[d7].x, t.x), fmaf(sg, y[d7].y, t.y));
            y[d7] = cmul(u, weff);
        }
    }

    // mask: lane holds H-freq index 7*brev6(lane)+d7
    int rb = (brev5(lane & 31) << 1) | (lane >> 5);
    const float* mrow = maskP + (size_t)L * Hn + 7 * rb;
#pragma unroll
    for (int d7 = 0; d7 < 7; ++d7) {
        float m = mrow[d7];
        y[d7].x *= m; y[d7].y *= m;
    }

    // inverse FFT64, DIT (sign-trick): y' = A + c*B, c = +-conj(wst)
#pragma unroll
    for (int s = 0; s < 6; ++s) {
        int dist = 1 << s;
        float2 wst = w64t[(lane & (dist - 1)) << (5 - s)];
        wst.y = -wst.y;
        bool hi = (lane & dist) != 0;
        float2 c = hi ? make_float2(-wst.x, -wst.y) : wst;
#pragma unroll
        for (int d7 = 0; d7 < 7; ++d7) {
            float2 t = shflx2(y[d7], dist);
            float2 B = hi ? y[d7] : t;
            float2 A = hi ? t : y[d7];
            y[d7] = cfma(c, B, A);
        }
    }
    // conj W448 twiddle + inverse DFT7 (Winograd) + LDS writeback
#pragma unroll
    for (int d7 = 1; d7 < 7; ++d7) {
        float2 c = make_float2(tp[d7].x, -tp[d7].y);
        y[d7] = cmul(y[d7], c);
    }
    dft7<-1>(y, xb);
#pragma unroll
    for (int b = 0; b < 7; ++b) ls[wv][64 * b + lane] = xb[b];
    __syncthreads();

    // stage out: mirror of stage in
#pragma unroll
    for (int m = 0; m < 4; ++m) {
        int j4 = tid + m * 256;
        if (j4 < 896) {
            int h = j4 >> 1, q = j4 & 1;
            float2 a = ls[2 * q][h];
            float2 b = ls[2 * q + 1][h];
            *(float4*)&base[(size_t)h * 8 + 2 * q] = make_float4(a.x, a.y, b.x, b.y);
        }
    }
}

// ---------- fused inverse row FFT + conj-coil + coil-sum + q/dot epilogue ----------
// Octet layout: each half-wave loads its 7 DIT-ready line-groups directly into
// registers. NO LDS staging, NO barriers in the coil loop.
// Coil loop split over gridDim.z: z-chunk zid handles ccz coils, accumulating
// into partial Qp[zid]; dots are linear in q so each z-chunk adds its partial.
__global__ __launch_bounds__(256) void k_irow_combine(const float2* __restrict__ Y1T,
                                                      const float2* __restrict__ coil,
                                                      const float2* __restrict__ P,
                                                      float2* __restrict__ Qp,
                                                      const float* __restrict__ miu,
                                                      double* __restrict__ S,
                                                      const float2* __restrict__ twg,
                                                      int ccz, int chunkStart,
                                                      int first, int last, int it) {
    __shared__ double sred[8];
    int tid = threadIdx.x;
    int lane = tid & 63, wv = tid >> 6, hi = lane >> 5, l32 = lane & 31;
    int h0 = blockIdx.x * 8, d = blockIdx.y;
    int zid = blockIdx.z;
    int zbase = zid * ccz;
    float2* Q = Qp + (size_t)zid * DHWn;
    int row = h0 + 2 * wv + hi;
    const float2* w32g = twg + TW_W32;
    const float2* t224 = twg + TW_T224;

    float2 tp[7];
#pragma unroll
    for (int d7 = 1; d7 < 7; ++d7) {
        float2 v = t224[d7 * 32 + l32];
        tp[d7] = make_float2(v.x, -v.y);   // conj (inverse twiddle)
    }

    float2 acc[7];
#pragma unroll
    for (int b = 0; b < 7; ++b) acc[b] = make_float2(0.f, 0.f);

    int oct0 = l32 >> 3, l8 = l32 & 7;
    for (int cz = 0; cz < ccz; ++cz) {
        const float2* ybase = Y1T + ((size_t)(zbase + cz) * Dn + d) * (size_t)HWn;
        const float2* crow = coil + (size_t)(chunkStart + zbase + cz) * HWn + (size_t)row * Wn;

        // DIT-ready register loads: y[d7] = line (d7*32+l32) at this row
        float2 y[7];
#pragma unroll
        for (int d7 = 0; d7 < 7; ++d7)
            y[d7] = ybase[(size_t)(4 * d7 + oct0) * OCT_F2 + (size_t)row * 8 + l8];
        float2 cpre[7];
#pragma unroll
        for (int b = 0; b < 7; ++b) cpre[b] = crow[32 * b + l32];

        // inverse FFT32 across half-wave, DIT (sign-trick): y' = A + c*B
#pragma unroll
        for (int s = 0; s < 5; ++s) {
            int dist = 1 << s;
            float2 wst = w32g[(l32 & (dist - 1)) << (4 - s)];
            wst.y = -wst.y;
            bool h2 = (l32 & dist) != 0;
            float2 c = h2 ? make_float2(-wst.x, -wst.y) : wst;
#pragma unroll
            for (int d7 = 0; d7 < 7; ++d7) {
                float2 t = shflx2(y[d7], dist);
                float2 B = h2 ? y[d7] : t;
                float2 A = h2 ? t : y[d7];
                y[d7] = cfma(c, B, A);
            }
        }
        // conj twiddle W224^{-l32*d7}
#pragma unroll
        for (int d7 = 1; d7 < 7; ++d7) y[d7] = cmul(y[d7], tp[d7]);
        // inverse DFT7 (Winograd) + conj-coil accumulate
        float2 s7[7];
        dft7<-1>(y, s7);
#pragma unroll
        for (int b = 0; b < 7; ++b) {
            float2 s = s7[b];
            float2 c = cpre[b];
            acc[b].x += fmaf(s.x, c.x, s.y * c.y);
            acc[b].y += fmaf(s.y, c.x, -s.x * c.y);
        }
    }

    // epilogue: partial q; only zid==0 folds in mu*p (exactly once in the sum).
    float mu = fabsf(miu[0]);
    const float2* prow = P + (size_t)d * HWn + (size_t)row * Wn;
    float2* qrow = Q + (size_t)d * HWn + (size_t)row * Wn;
    double ar = 0.0, ai = 0.0;
#pragma unroll
    for (int b = 0; b < 7; ++b) {
        float2 pv = prow[32 * b + l32];
        float2 s0;
        if (first) {
            if (zid == 0) s0 = make_float2(fmaf(mu, pv.x, acc[b].x), fmaf(mu, pv.y, acc[b].y));
            else          s0 = acc[b];
        } else {
            float2 qv = qrow[32 * b + l32];
            s0 = cadd(qv, acc[b]);
        }
        qrow[32 * b + l32] = s0;
        if (last) {
            ar += (double)(s0.x * pv.x + s0.y * pv.y);
            ai += (double)(s0.y * pv.x - s0.x * pv.y);
        }
    }
    if (last) {
        ar = waveReduce(ar);
        ai = waveReduce(ai);
        if (lane == 0) { sred[wv] = ar; sred[4 + wv] = ai; }
        __syncthreads();
        if (tid == 0) {
            atomicAdd(&S[8 + it],  sred[0] + sred[1] + sred[2] + sred[3]);
            atomicAdd(&S[16 + it], sred[4] + sred[5] + sred[6] + sred[7]);
        }
    }
}

// ---------- CG scalar update (float4 = 2 complex per lane) ----------
// q points at nz partial buffers, each N2 float4s; summed inline.
// (update_p is fused into the next iteration's k_rowfft0.)
__global__ void k_update_br(const double* __restrict__ Sin, double* __restrict__ S, int it,
                            const float4* __restrict__ p, const float4* __restrict__ q,
                            int nz,
                            float4* __restrict__ b, float4* __restrict__ r) {
    double rr = Sin[it], qr = Sin[8 + it], qi = Sin[16 + it];
    double den = qr * qr + qi * qi;
    float arf = (float)(rr * qr / den);
    float aif = (float)(-rr * qi / den);
    double acc = 0.0;
    const int N2 = DHWn / 2;
    for (int e = blockIdx.x * blockDim.x + threadIdx.x; e < N2; e += gridDim.x * blockDim.x) {
        float4 pv = p[e], bv = b[e], rv = r[e];
        float4 qv = q[e];
        for (int z = 1; z < nz; ++z) {
            float4 t = q[(size_t)z * N2 + e];
            qv.x += t.x; qv.y += t.y; qv.z += t.z; qv.w += t.w;
        }
        bv.x += arf * pv.x - aif * pv.y;  bv.y += arf * pv.y + aif * pv.x;
        bv.z += arf * pv.z - aif * pv.w;  bv.w += arf * pv.w + aif * pv.z;
        b[e] = bv;
        rv.x -= arf * qv.x - aif * qv.y;  rv.y -= arf * qv.y + aif * qv.x;
        rv.z -= arf * qv.z - aif * qv.w;  rv.w -= arf * qv.w + aif * qv.z;
        r[e] = rv;
        acc += (double)rv.x * rv.x + (double)rv.y * rv.y
             + (double)rv.z * rv.z + (double)rv.w * rv.w;
    }
    acc = waveReduce(acc);
    if ((threadIdx.x & 63) == 0) atomicAdd(&S[it + 1], acc);
}

__global__ void k_output(const float2* __restrict__ b, float* __restrict__ out) {
    for (int e = blockIdx.x * blockDim.x + threadIdx.x; e < DHWn; e += gridDim.x * blockDim.x) {
        int d = e / HWn, rem = e - d * HWn;
        int h = rem / Wn, w = rem - h * Wn;
        int hs = h + Hn / 2; if (hs >= Hn) hs -= Hn;
        int ws = w + Wn / 2; if (ws >= Wn) ws -= Wn;
        float2 v = b[d * HWn + hs * Wn + ws];
        out[e] = v.x;
        out[DHWn + e] = v.y;
    }
}

extern "C" void kernel_launch(void* const* d_in, const int* in_sizes, int n_in,
                              void* d_out, int out_size, void* d_ws, size_t ws_size,
                              hipStream_t stream) {
    const float* z      = (const float*)d_in[0];
    const float* zf     = (const float*)d_in[1];
    const float* coil_r = (const float*)d_in[2];
    const float* coil_i = (const float*)d_in[3];
    const int*   maskp  = (const int*)d_in[4];
    const float* miu    = (const float*)d_in[5];
    float* out = (float*)d_out;

    char* w = (char*)d_ws;
    size_t off = 0;
    auto carve = [&](size_t bytes) -> void* {
        void* ptr = w + off;
        off += (bytes + 511) & ~(size_t)511;
        return ptr;
    };
    float2* P0    = (float2*)carve((size_t)DHWn * 8);
    float2* P1    = (float2*)carve((size_t)DHWn * 8);
    float2* R     = (float2*)carve((size_t)DHWn * 8);
    float2* Bv    = (float2*)carve((size_t)DHWn * 8);
    float2* COIL  = (float2*)carve((size_t)Cn * HWn * 8);
    float*  MASKP = (float*)carve((size_t)HWn * 4);
    float2* TWS   = (float2*)carve(TW_NT * 8);
    double* S     = (double*)carve(64 * 8);

    size_t imgSet = (size_t)DHWn * 8;   // one coil-slot (12 slices), 9.63 MB
    // (coils staged per chunk, z-splits of the combine); NZ divides cc.
    int cc = 1, NZ = 1;
    {
        const int cand[6][2] = {{10,2},{10,1},{5,1},{2,1},{1,1},{1,1}};
        for (int i = 0; i < 6; ++i) {
            size_t need = off + (size_t)(cand[i][0] + cand[i][1]) * imgSet;
            if (need <= ws_size) { cc = cand[i][0]; NZ = cand[i][1]; break; }
        }
    }
    float2* Qp  = (float2*)carve((size_t)NZ * imgSet);   // NZ partial-q buffers
    float2* Y1T = (float2*)carve((size_t)cc * imgSet);   // staged slices [c][d][oct][h][l8]
    int nch = Cn / cc;
    int ccz = cc / NZ;

    k_init_misc<<<1, 1024, 0, stream>>>(TWS, S);
    k_build_p<<<1024, 256, 0, stream>>>(z, zf, miu, P0, R, Bv, S);
    k_build_coil<<<1024, 256, 0, stream>>>(coil_r, coil_i, COIL);
    k_build_mask<<<512, 256, 0, stream>>>(maskp, MASKP);

    for (int it = 0; it < 5; ++it) {
        float2* Pcur = (it & 1) ? P1 : P0;     // p for this iteration
        float2* Pold = (it & 1) ? P0 : P1;     // previous p (read source for it>=1)
        const float2* Pread = (it == 0) ? Pcur : Pold;
        for (int ch = 0; ch < nch; ++ch) {
            int cs = ch * cc;
            dim3 gf(Hn / 8, Dn, cc);    // 56 x 12 x cc
            dim3 gc(28, 24, cc);        // octet x (d + 12*half) x cc
            dim3 gi(Hn / 8, Dn, NZ);    // 56 x 12 x NZ, each z does cc/NZ coils
            k_rowfft0<<<gf, 256, 0, stream>>>(Pread, R, Pcur, COIL, Y1T, TWS, S, cs, it);
            k_colfft<<<gc, 256, 0, stream>>>(Y1T, MASKP, TWS);
            k_irow_combine<<<gi, 256, 0, stream>>>(Y1T, COIL, Pcur, Qp, miu, S, TWS,
                                                   ccz, cs, ch == 0 ? 1 : 0,
                                                   ch == nch - 1 ? 1 : 0, it);
        }
        k_update_br<<<1024, 256, 0, stream>>>(S, S, it, (const float4*)Pcur, (const float4*)Qp,
                                              NZ, (float4*)Bv, (float4*)R);
    }
    k_output<<<1024, 256, 0, stream>>>(Bv, out);
}

// Round 14
// 1081.992 us; speedup vs baseline: 1.0376x; 1.0155x over previous
//
#include <hip/hip_runtime.h>
#include <math.h>

// Problem constants (fixed shapes from setup_inputs)
#define Dn   12
#define Hn   448
#define Wn   224
#define HWn  (Hn*Wn)        // 100352
#define DHWn (Dn*HWn)       // 1204224
#define Cn   10

// Y1T layout is OCTET-BLOCKED per slice (c,d): element (L, h) stored at
//   (L>>3)*3584 + h*8 + (L&7)        (3584 = 448*8; octet = 28 KB contiguous)
// where L is the bit-rev-permuted line index (identity L = d7*32+l32).
// - colfft: one block per HALF-octet (4 lines); the two halves of an octet are
//   placed 336 bids apart (= 0 mod 8) so they land on the SAME XCD and share L2.
// - rowfft stores / irow loads: per d7, 64-B segments; adjacent-row half-waves
//   complete each 128-B cache line -> no over-fetch.
#define OCT_F2 3584

// Twiddle table (float2 in global):
#define TW_W32   0     // 16:  W32^j
#define TW_W7    16    // 7:   W7^j (unused by Winograd path, kept for layout)
#define TW_W64   23    // 32:  W64^j
#define TW_T224  55    // 224: W224^{d7*l32}  [d7*32+l32]
#define TW_T448  279   // 448: W448^{d7*lane} [d7*64+lane]
#define TW_NT    727

// ---------- complex helpers ----------
__device__ __forceinline__ float2 cmul(float2 a, float2 b) {
    return make_float2(fmaf(a.x, b.x, -a.y * b.y), fmaf(a.x, b.y, a.y * b.x));
}
__device__ __forceinline__ float2 cfma(float2 a, float2 b, float2 acc) {
    acc.x = fmaf(a.x, b.x, fmaf(-a.y, b.y, acc.x));
    acc.y = fmaf(a.x, b.y, fmaf(a.y, b.x, acc.y));
    return acc;
}
__device__ __forceinline__ float2 cadd(float2 a, float2 b) { return make_float2(a.x + b.x, a.y + b.y); }
__device__ __forceinline__ float2 csub(float2 a, float2 b) { return make_float2(a.x - b.x, a.y - b.y); }
__host__ __device__ constexpr int brev5(int i) {
    return ((i & 1) << 4) | ((i & 2) << 2) | (i & 4) | ((i & 8) >> 2) | ((i & 16) >> 4);
}

__device__ __forceinline__ float2 shflx2(float2 v, int m) {
    return make_float2(__shfl_xor(v.x, m, 64), __shfl_xor(v.y, m, 64));
}

// v_permlane32_swap_b32 (VALU pipe, not LDS): swaps a.hi with b.lo ->
// returns a'={a.lo, b.lo}, b'={a.hi, b.hi}.
typedef unsigned int uv2 __attribute__((ext_vector_type(2)));
__device__ __forceinline__ void swap32f(float &a, float &b) {
    uv2 r = __builtin_amdgcn_permlane32_swap(__float_as_uint(a), __float_as_uint(b), false, false);
    a = __uint_as_float(r.x);
    b = __uint_as_float(r.y);
}

__device__ __forceinline__ double waveReduce(double v) {
#pragma unroll
    for (int o = 32; o > 0; o >>= 1) v += __shfl_down(v, o, 64);
    return v;
}

// ---------- Winograd-style DFT-7 (66 VALU ops vs 168 naive) ----------
// Forward (SGN=+1): y[k] = Sum_n x[n] exp(-2*pi*i*n*k/7) = A_k - i*B_k
// Inverse (SGN=-1): conj twiddles -> y[k] = A_k + i*B_k
template<int SGN>
__device__ __forceinline__ void dft7(const float2* __restrict__ x, float2* __restrict__ y) {
    const float c1 =  0.62348980185873359f;   // cos(2pi/7)
    const float c2 = -0.22252093395631445f;   // cos(4pi/7)
    const float c3 = -0.90096886790241915f;   // cos(6pi/7)
    const float s1 =  0.78183148246802980f;   // sin(2pi/7)
    const float s2 =  0.97492791218182362f;   // sin(4pi/7)
    const float s3 =  0.43388373911755823f;   // sin(6pi/7)
    float2 u1 = cadd(x[1], x[6]), v1 = csub(x[1], x[6]);
    float2 u2 = cadd(x[2], x[5]), v2 = csub(x[2], x[5]);
    float2 u3 = cadd(x[3], x[4]), v3 = csub(x[3], x[4]);
    y[0] = make_float2(x[0].x + u1.x + u2.x + u3.x,
                       x[0].y + u1.y + u2.y + u3.y);
    float2 A1, A2, A3, B1, B2, B3;
    A1.x = fmaf(c1, u1.x, fmaf(c2, u2.x, fmaf(c3, u3.x, x[0].x)));
    A1.y = fmaf(c1, u1.y, fmaf(c2, u2.y, fmaf(c3, u3.y, x[0].y)));
    A2.x = fmaf(c2, u1.x, fmaf(c3, u2.x, fmaf(c1, u3.x, x[0].x)));
    A2.y = fmaf(c2, u1.y, fmaf(c3, u2.y, fmaf(c1, u3.y, x[0].y)));
    A3.x = fmaf(c3, u1.x, fmaf(c1, u2.x, fmaf(c2, u3.x, x[0].x)));
    A3.y = fmaf(c3, u1.y, fmaf(c1, u2.y, fmaf(c2, u3.y, x[0].y)));
    B1.x = fmaf(s1, v1.x, fmaf(s2, v2.x,  s3 * v3.x));
    B1.y = fmaf(s1, v1.y, fmaf(s2, v2.y,  s3 * v3.y));
    B2.x = fmaf(s2, v1.x, fmaf(-s3, v2.x, -s1 * v3.x));
    B2.y = fmaf(s2, v1.y, fmaf(-s3, v2.y, -s1 * v3.y));
    B3.x = fmaf(s3, v1.x, fmaf(-s1, v2.x,  s2 * v3.x));
    B3.y = fmaf(s3, v1.y, fmaf(-s1, v2.y,  s2 * v3.y));
    if (SGN > 0) {
        y[1] = make_float2(A1.x + B1.y, A1.y - B1.x);
        y[6] = make_float2(A1.x - B1.y, A1.y + B1.x);
        y[2] = make_float2(A2.x + B2.y, A2.y - B2.x);
        y[5] = make_float2(A2.x - B2.y, A2.y + B2.x);
        y[3] = make_float2(A3.x + B3.y, A3.y - B3.x);
        y[4] = make_float2(A3.x - B3.y, A3.y + B3.x);
    } else {
        y[1] = make_float2(A1.x - B1.y, A1.y + B1.x);
        y[6] = make_float2(A1.x + B1.y, A1.y - B1.x);
        y[2] = make_float2(A2.x - B2.y, A2.y + B2.x);
        y[5] = make_float2(A2.x + B2.y, A2.y - B2.x);
        y[3] = make_float2(A3.x - B3.y, A3.y + B3.x);
        y[4] = make_float2(A3.x + B3.y, A3.y - B3.x);
    }
}

// ---------- init kernels ----------
__global__ void k_init_misc(float2* __restrict__ tws, double* __restrict__ S) {
    int t = threadIdx.x;  // 1024 threads
    const double PI2 = 6.283185307179586476925287;
    if (t < 16)              { double s, c; sincos(-(PI2 * t) / 32.0, &s, &c); tws[TW_W32 + t] = make_float2((float)c, (float)s); }
    if (t >= 16 && t < 23)   { int j = t - 16; double s, c; sincos(-(PI2 * j) / 7.0,  &s, &c); tws[TW_W7 + j]  = make_float2((float)c, (float)s); }
    if (t >= 23 && t < 55)   { int j = t - 23; double s, c; sincos(-(PI2 * j) / 64.0, &s, &c); tws[TW_W64 + j] = make_float2((float)c, (float)s); }
    if (t >= 55 && t < 279)  { int j = t - 55;  int d7 = j >> 5, l = j & 31;
                               double s, c; sincos(-(PI2 * (d7 * l)) / 224.0, &s, &c);
                               tws[TW_T224 + j] = make_float2((float)c, (float)s); }
    if (t >= 279 && t < 727) { int j = t - 279; int d7 = j >> 6, l = j & 63;
                               double s, c; sincos(-(PI2 * (d7 * l)) / 448.0, &s, &c);
                               tws[TW_T448 + j] = make_float2((float)c, (float)s); }
    if (t >= 727 && t < 759) S[t - 727] = 0.0;
}

__global__ void k_build_p(const float* __restrict__ z, const float* __restrict__ zf,
                          const float* __restrict__ miu,
                          float2* __restrict__ p, float2* __restrict__ r, float2* __restrict__ b,
                          double* __restrict__ S) {
    float mu = fabsf(miu[0]);
    double acc = 0.0;
    for (int e = blockIdx.x * blockDim.x + threadIdx.x; e < DHWn; e += gridDim.x * blockDim.x) {
        int d = e / HWn, rem = e - d * HWn;
        int h = rem / Wn, w = rem - h * Wn;
        int hs = h + Hn / 2; if (hs >= Hn) hs -= Hn;
        int ws = w + Wn / 2; if (ws >= Wn) ws -= Wn;
        int src = d * HWn + hs * Wn + ws;
        float pr = fmaf(mu, z[src], zf[src]);
        float pi = fmaf(mu, z[DHWn + src], zf[DHWn + src]);
        float2 v = make_float2(pr, pi);
        p[e] = v; r[e] = v; b[e] = make_float2(0.f, 0.f);
        acc += (double)pr * pr + (double)pi * pi;
    }
    acc = waveReduce(acc);
    if ((threadIdx.x & 63) == 0) atomicAdd(&S[0], acc);
}

__global__ void k_build_coil(const float* __restrict__ cr, const float* __restrict__ ci,
                             float2* __restrict__ coil) {
    for (int e = blockIdx.x * blockDim.x + threadIdx.x; e < Cn * HWn; e += gridDim.x * blockDim.x) {
        int c = e / HWn, rem = e - c * HWn;
        int h = rem / Wn, w = rem - h * Wn;
        int hs = h + Hn / 2; if (hs >= Hn) hs -= Hn;
        int ws = w + Wn / 2; if (ws >= Wn) ws -= Wn;
        int src = c * HWn + hs * Wn + ws;
        coil[e] = make_float2(cr[src], ci[src]);
    }
}

// permuted + shifted + scaled mask: maskP[L*448 + h], line L holds true
// frequency column w(L) = 7*brev5(L&31) + (L>>5)
__global__ void k_build_mask(const int* __restrict__ mask, float* __restrict__ maskP) {
    for (int e = blockIdx.x * blockDim.x + threadIdx.x; e < HWn; e += gridDim.x * blockDim.x) {
        int L = e / Hn, h = e - L * Hn;
        int w = 7 * brev5(L & 31) + (L >> 5);
        int hs = h + Hn / 2; if (hs >= Hn) hs -= Hn;
        int ws = w + Wn / 2; if (ws >= Wn) ws -= Wn;
        maskP[e] = (float)mask[hs * Wn + ws] * (1.0f / (float)HWn);
    }
}

// ---------- forward row FFT (224 = 7*32 lane-FFT), coil-mul, direct octet store ----------
// No LDS, no barriers. FUSED update_p: for it>=1, p = r + beta*p_old on the fly;
// global-coil-0 block stores p into Pnew (ping-pong, no races).
__global__ __launch_bounds__(256) void k_rowfft0(const float2* __restrict__ Pread,
                                                 const float2* __restrict__ Rv,
                                                 float2* __restrict__ Pnew,
                                                 const float2* __restrict__ coil,
                                                 float2* __restrict__ Y1T,
                                                 const float2* __restrict__ twg,
                                                 const double* __restrict__ S,
                                                 int chunkStart, int it) {
    int tid = threadIdx.x;
    int lane = tid & 63, wv = tid >> 6, hi = lane >> 5, l32 = lane & 31;
    int h0 = blockIdx.x * 8, d = blockIdx.y, cz = blockIdx.z;
    int row = h0 + 2 * wv + hi;
    const float2* w32g = twg + TW_W32;
    const float2* t224 = twg + TW_T224;

    size_t roff = (size_t)d * HWn + (size_t)row * Wn;
    const float2* prow = Pread + roff;
    const float2* crow = coil + (size_t)(chunkStart + cz) * HWn + (size_t)row * Wn;

    float2 pv[7];
    if (it == 0) {
#pragma unroll
        for (int b = 0; b < 7; ++b) pv[b] = prow[32 * b + l32];
    } else {
        float beta = (float)(S[it] / S[it - 1]);
        const float2* rrow = Rv + roff;
#pragma unroll
        for (int b = 0; b < 7; ++b) {
            float2 rv = rrow[32 * b + l32];
            float2 po = prow[32 * b + l32];
            pv[b] = make_float2(fmaf(beta, po.x, rv.x), fmaf(beta, po.y, rv.y));
        }
        if (chunkStart + cz == 0) {
            float2* pw = Pnew + roff;
#pragma unroll
            for (int b = 0; b < 7; ++b) pw[32 * b + l32] = pv[b];
        }
    }

    float2 xb[7];
#pragma unroll
    for (int b = 0; b < 7; ++b) xb[b] = cmul(pv[b], crow[32 * b + l32]);

    // DFT7 (Winograd)
    float2 y[7];
    dft7<1>(xb, y);
    // twiddle W224^{l32*d7} from table
#pragma unroll
    for (int d7 = 1; d7 < 7; ++d7) y[d7] = cmul(y[d7], t224[d7 * 32 + l32]);

    // FFT32 across each half-wave, DIF (sign-trick form: y' = (t + s*y)*weff)
#pragma unroll
    for (int s = 0; s < 5; ++s) {
        int dist = 16 >> s;
        float2 wst = w32g[(l32 & (dist - 1)) << s];
        bool h2 = (l32 & dist) != 0;
        float sg = h2 ? -1.f : 1.f;
        float2 weff = h2 ? wst : make_float2(1.f, 0.f);
#pragma unroll
        for (int d7 = 0; d7 < 7; ++d7) {
            float2 t = shflx2(y[d7], dist);
            float2 u = make_float2(fmaf(sg, y[d7].x, t.x), fmaf(sg, y[d7].y, t.y));
            y[d7] = cmul(u, weff);
        }
    }

    // direct store: line L = d7*32+l32 -> octet (L>>3), slot (L&7)
    float2* ybase = Y1T + ((size_t)cz * Dn + d) * (size_t)HWn;
    int oct0 = l32 >> 3, l8 = l32 & 7;
#pragma unroll
    for (int d7 = 0; d7 < 7; ++d7)
        ybase[(size_t)(4 * d7 + oct0) * OCT_F2 + (size_t)row * 8 + l8] = y[d7];
}

// ---------- column FFT448 + mask + IFFT448 ----------
// 256 threads = 4 waves; one block per HALF-octet (4 lines, 1 line/wave).
// dist-32 exchanges for reg-pairs go through v_permlane32_swap (VALU pipe)
// instead of ds_swizzle (LDS pipe) -- the LDS crossbar is the contended
// resource (shfl = ds-op on CDNA). Packed half-layout is bit-identical
// arithmetic; mask indexing adjusted (subtree bit fixed per reg).
#define CP 452
__global__ __launch_bounds__(256) void k_colfft(float2* __restrict__ Y1T,
                                                const float* __restrict__ maskP,
                                                const float2* __restrict__ twg) {
    __shared__ float2 ls[4][CP];
    int tid = threadIdx.x;               // 0..255
    int lane = tid & 63, wv = tid >> 6;  // 4 waves
    int oct = blockIdx.x;                // 28
    int byy = blockIdx.y;                // 24 = d + 12*half
    int d = (byy < 12) ? byy : byy - 12;
    int half = (byy < 12) ? 0 : 1;
    int cz = blockIdx.z;
    const float2* w64t = twg + TW_W64;
    const float2* t448 = twg + TW_T448;

    float2* base = Y1T + ((size_t)cz * Dn + d) * (size_t)HWn + (size_t)oct * OCT_F2
                 + 4 * half;             // slots 4*half .. 4*half+3

    // stage in: 448 h x 4 slots = 1792 f2 = 896 f4 (two f4 per h)
#pragma unroll
    for (int m = 0; m < 4; ++m) {
        int j4 = tid + m * 256;
        if (j4 < 896) {
            int h = j4 >> 1, q = j4 & 1;     // f4 covers local slots 2q, 2q+1 at col h
            float4 v = *(const float4*)&base[(size_t)h * 8 + 2 * q];
            ls[2 * q][h]     = make_float2(v.x, v.y);
            ls[2 * q + 1][h] = make_float2(v.z, v.w);
        }
    }
    __syncthreads();

    int L = oct * 8 + 4 * half + wv;     // this wave's line

    float2 xb[7];
#pragma unroll
    for (int b = 0; b < 7; ++b) xb[b] = ls[wv][64 * b + lane];

    // twiddles W448^{lane*d7} (reused conjugated in the inverse pass)
    float2 tp[7];
#pragma unroll
    for (int d7 = 1; d7 < 7; ++d7) tp[d7] = t448[d7 * 64 + lane];

    // forward DFT7 (Winograd) + W448 twiddle
    float2 y[7];
    dft7<1>(xb, y);
#pragma unroll
    for (int d7 = 1; d7 < 7; ++d7) y[d7] = cmul(y[d7], tp[d7]);

    // ---- forward FFT64, stage dist=32 ----
    // pairs (0,1),(2,3),(4,5): permlane-packed. After this, reg 2p holds the
    // sum/even subtree {u_even | v_even} and reg 2p+1 the dif/odd subtree.
    {
        float2 wst = w64t[lane & 31];
#pragma unroll
        for (int p = 0; p < 3; ++p) {
            float2 u = y[2 * p], v = y[2 * p + 1];
            swap32f(u.x, v.x); swap32f(u.y, v.y);    // u={lo_u,lo_v}, v={hi_u,hi_v}
            y[2 * p]     = cadd(u, v);               // S (no twiddle)
            y[2 * p + 1] = cmul(csub(u, v), wst);    // D * w
        }
        // y[6] classic
        bool hb = lane >= 32;
        float sg = hb ? -1.f : 1.f;
        float2 weff = hb ? wst : make_float2(1.f, 0.f);
        float2 t = shflx2(y[6], 32);
        float2 u6 = make_float2(fmaf(sg, y[6].x, t.x), fmaf(sg, y[6].y, t.y));
        y[6] = cmul(u6, weff);
    }
    // stages dist=16..1 (within 32-halves; identical for packed regs)
#pragma unroll
    for (int s = 1; s < 6; ++s) {
        int dist = 32 >> s;
        float2 wst = w64t[(lane & (dist - 1)) << s];
        bool hb = (lane & dist) != 0;
        float sg = hb ? -1.f : 1.f;
        float2 weff = hb ? wst : make_float2(1.f, 0.f);
#pragma unroll
        for (int d7 = 0; d7 < 7; ++d7) {
            float2 t = shflx2(y[d7], dist);
            float2 u = make_float2(fmaf(sg, y[d7].x, t.x), fmaf(sg, y[d7].y, t.y));
            y[d7] = cmul(u, weff);
        }
    }

    // mask. Unpacked H-freq index: 7*(brev5(lane&31)<<1 | (lane>>5)) + d7.
    // Packed regs: subtree bit is 0 for S-regs (2p), 1 for D-regs (2p+1);
    // d7 = 2p for lanes<32 (u), 2p+1 for lanes>=32 (v).
    {
        int rb0 = brev5(lane & 31) << 1;
        const float* mbase = maskP + (size_t)L * Hn;
        bool lo = lane < 32;
#pragma unroll
        for (int p = 0; p < 3; ++p) {
            int dsel = lo ? (2 * p) : (2 * p + 1);
            float mS = mbase[7 * rb0 + dsel];
            float mD = mbase[7 * (rb0 + 1) + dsel];
            y[2 * p].x *= mS;     y[2 * p].y *= mS;
            y[2 * p + 1].x *= mD; y[2 * p + 1].y *= mD;
        }
        int rb6 = rb0 | (lane >> 5);
        float m6 = mbase[7 * rb6 + 6];
        y[6].x *= m6; y[6].y *= m6;
    }

    // inverse FFT64, DIT stages dist=1..16 (within halves; packed-safe)
#pragma unroll
    for (int s = 0; s < 5; ++s) {
        int dist = 1 << s;
        float2 wst = w64t[(lane & (dist - 1)) << (5 - s)];
        wst.y = -wst.y;
        bool hb = (lane & dist) != 0;
        float2 c = hb ? make_float2(-wst.x, -wst.y) : wst;
#pragma unroll
        for (int d7 = 0; d7 < 7; ++d7) {
            float2 t = shflx2(y[d7], dist);
            float2 B = hb ? y[d7] : t;
            float2 A = hb ? t : y[d7];
            y[d7] = cfma(c, B, A);
        }
    }
    // ---- final inverse stage dist=32 ----
    {
        float2 wst = w64t[lane & 31];
        float2 cw  = make_float2(wst.x, -wst.y);    // conj
        float2 ncw = make_float2(-cw.x, -cw.y);
#pragma unroll
        for (int p = 0; p < 3; ++p) {
            float2 S = y[2 * p], D = y[2 * p + 1];  // S={u_e,v_e}, D={u_o,v_o}
            float2 T1 = cfma(cw,  D, S);            // even + cw*odd  -> out.lo
            float2 T2 = cfma(ncw, D, S);            // even - cw*odd  -> out.hi
            swap32f(T1.x, T2.x); swap32f(T1.y, T2.y);  // -> (u_out, v_out)
            y[2 * p] = T1; y[2 * p + 1] = T2;
        }
        // y[6] classic
        bool hb = lane >= 32;
        float2 c = hb ? ncw : cw;
        float2 t = shflx2(y[6], 32);
        float2 B = hb ? y[6] : t;
        float2 A = hb ? t : y[6];
        y[6] = cfma(c, B, A);
    }

    // conj W448 twiddle + inverse DFT7 (Winograd) + LDS writeback
#pragma unroll
    for (int d7 = 1; d7 < 7; ++d7) {
        float2 c = make_float2(tp[d7].x, -tp[d7].y);
        y[d7] = cmul(y[d7], c);
    }
    dft7<-1>(y, xb);
#pragma unroll
    for (int b = 0; b < 7; ++b) ls[wv][64 * b + lane] = xb[b];
    __syncthreads();

    // stage out: mirror of stage in
#pragma unroll
    for (int m = 0; m < 4; ++m) {
        int j4 = tid + m * 256;
        if (j4 < 896) {
            int h = j4 >> 1, q = j4 & 1;
            float2 a = ls[2 * q][h];
            float2 b = ls[2 * q + 1][h];
            *(float4*)&base[(size_t)h * 8 + 2 * q] = make_float4(a.x, a.y, b.x, b.y);
        }
    }
}

// ---------- fused inverse row FFT + conj-coil + coil-sum + q/dot epilogue ----------
// Octet layout: each half-wave loads its 7 DIT-ready line-groups directly into
// registers. NO LDS staging, NO barriers in the coil loop.
// Coil loop split over gridDim.z into partial Qp[zid]; dots are linear in q.
__global__ __launch_bounds__(256) void k_irow_combine(const float2* __restrict__ Y1T,
                                                      const float2* __restrict__ coil,
                                                      const float2* __restrict__ P,
                                                      float2* __restrict__ Qp,
                                                      const float* __restrict__ miu,
                                                      double* __restrict__ S,
                                                      const float2* __restrict__ twg,
                                                      int ccz, int chunkStart,
                                                      int first, int last, int it) {
    __shared__ double sred[8];
    int tid = threadIdx.x;
    int lane = tid & 63, wv = tid >> 6, hi = lane >> 5, l32 = lane & 31;
    int h0 = blockIdx.x * 8, d = blockIdx.y;
    int zid = blockIdx.z;
    int zbase = zid * ccz;
    float2* Q = Qp + (size_t)zid * DHWn;
    int row = h0 + 2 * wv + hi;
    const float2* w32g = twg + TW_W32;
    const float2* t224 = twg + TW_T224;

    float2 tp[7];
#pragma unroll
    for (int d7 = 1; d7 < 7; ++d7) {
        float2 v = t224[d7 * 32 + l32];
        tp[d7] = make_float2(v.x, -v.y);   // conj (inverse twiddle)
    }

    float2 acc[7];
#pragma unroll
    for (int b = 0; b < 7; ++b) acc[b] = make_float2(0.f, 0.f);

    int oct0 = l32 >> 3, l8 = l32 & 7;
    for (int cz = 0; cz < ccz; ++cz) {
        const float2* ybase = Y1T + ((size_t)(zbase + cz) * Dn + d) * (size_t)HWn;
        const float2* crow = coil + (size_t)(chunkStart + zbase + cz) * HWn + (size_t)row * Wn;

        // DIT-ready register loads: y[d7] = line (d7*32+l32) at this row
        float2 y[7];
#pragma unroll
        for (int d7 = 0; d7 < 7; ++d7)
            y[d7] = ybase[(size_t)(4 * d7 + oct0) * OCT_F2 + (size_t)row * 8 + l8];
        float2 cpre[7];
#pragma unroll
        for (int b = 0; b < 7; ++b) cpre[b] = crow[32 * b + l32];

        // inverse FFT32 across half-wave, DIT (sign-trick): y' = A + c*B
#pragma unroll
        for (int s = 0; s < 5; ++s) {
            int dist = 1 << s;
            float2 wst = w32g[(l32 & (dist - 1)) << (4 - s)];
            wst.y = -wst.y;
            bool h2 = (l32 & dist) != 0;
            float2 c = h2 ? make_float2(-wst.x, -wst.y) : wst;
#pragma unroll
            for (int d7 = 0; d7 < 7; ++d7) {
                float2 t = shflx2(y[d7], dist);
                float2 B = h2 ? y[d7] : t;
                float2 A = h2 ? t : y[d7];
                y[d7] = cfma(c, B, A);
            }
        }
        // conj twiddle W224^{-l32*d7}
#pragma unroll
        for (int d7 = 1; d7 < 7; ++d7) y[d7] = cmul(y[d7], tp[d7]);
        // inverse DFT7 (Winograd) + conj-coil accumulate
        float2 s7[7];
        dft7<-1>(y, s7);
#pragma unroll
        for (int b = 0; b < 7; ++b) {
            float2 s = s7[b];
            float2 c = cpre[b];
            acc[b].x += fmaf(s.x, c.x, s.y * c.y);
            acc[b].y += fmaf(s.y, c.x, -s.x * c.y);
        }
    }

    // epilogue: partial q; only zid==0 folds in mu*p (exactly once in the sum).
    float mu = fabsf(miu[0]);
    const float2* prow = P + (size_t)d * HWn + (size_t)row * Wn;
    float2* qrow = Q + (size_t)d * HWn + (size_t)row * Wn;
    double ar = 0.0, ai = 0.0;
#pragma unroll
    for (int b = 0; b < 7; ++b) {
        float2 pv = prow[32 * b + l32];
        float2 s0;
        if (first) {
            if (zid == 0) s0 = make_float2(fmaf(mu, pv.x, acc[b].x), fmaf(mu, pv.y, acc[b].y));
            else          s0 = acc[b];
        } else {
            float2 qv = qrow[32 * b + l32];
            s0 = cadd(qv, acc[b]);
        }
        qrow[32 * b + l32] = s0;
        if (last) {
            ar += (double)(s0.x * pv.x + s0.y * pv.y);
            ai += (double)(s0.y * pv.x - s0.x * pv.y);
        }
    }
    if (last) {
        ar = waveReduce(ar);
        ai = waveReduce(ai);
        if (lane == 0) { sred[wv] = ar; sred[4 + wv] = ai; }
        __syncthreads();
        if (tid == 0) {
            atomicAdd(&S[8 + it],  sred[0] + sred[1] + sred[2] + sred[3]);
            atomicAdd(&S[16 + it], sred[4] + sred[5] + sred[6] + sred[7]);
        }
    }
}

// ---------- CG scalar update (float4 = 2 complex per lane) ----------
// q points at nz partial buffers, each N2 float4s; summed inline.
// (update_p is fused into the next iteration's k_rowfft0.)
__global__ void k_update_br(const double* __restrict__ Sin, double* __restrict__ S, int it,
                            const float4* __restrict__ p, const float4* __restrict__ q,
                            int nz,
                            float4* __restrict__ b, float4* __restrict__ r) {
    double rr = Sin[it], qr = Sin[8 + it], qi = Sin[16 + it];
    double den = qr * qr + qi * qi;
    float arf = (float)(rr * qr / den);
    float aif = (float)(-rr * qi / den);
    double acc = 0.0;
    const int N2 = DHWn / 2;
    for (int e = blockIdx.x * blockDim.x + threadIdx.x; e < N2; e += gridDim.x * blockDim.x) {
        float4 pv = p[e], bv = b[e], rv = r[e];
        float4 qv = q[e];
        for (int z = 1; z < nz; ++z) {
            float4 t = q[(size_t)z * N2 + e];
            qv.x += t.x; qv.y += t.y; qv.z += t.z; qv.w += t.w;
        }
        bv.x += arf * pv.x - aif * pv.y;  bv.y += arf * pv.y + aif * pv.x;
        bv.z += arf * pv.z - aif * pv.w;  bv.w += arf * pv.w + aif * pv.z;
        b[e] = bv;
        rv.x -= arf * qv.x - aif * qv.y;  rv.y -= arf * qv.y + aif * qv.x;
        rv.z -= arf * qv.z - aif * qv.w;  rv.w -= arf * qv.w + aif * qv.z;
        r[e] = rv;
        acc += (double)rv.x * rv.x + (double)rv.y * rv.y
             + (double)rv.z * rv.z + (double)rv.w * rv.w;
    }
    acc = waveReduce(acc);
    if ((threadIdx.x & 63) == 0) atomicAdd(&S[it + 1], acc);
}

__global__ void k_output(const float2* __restrict__ b, float* __restrict__ out) {
    for (int e = blockIdx.x * blockDim.x + threadIdx.x; e < DHWn; e += gridDim.x * blockDim.x) {
        int d = e / HWn, rem = e - d * HWn;
        int h = rem / Wn, w = rem - h * Wn;
        int hs = h + Hn / 2; if (hs >= Hn) hs -= Hn;
        int ws = w + Wn / 2; if (ws >= Wn) ws -= Wn;
        float2 v = b[d * HWn + hs * Wn + ws];
        out[e] = v.x;
        out[DHWn + e] = v.y;
    }
}

extern "C" void kernel_launch(void* const* d_in, const int* in_sizes, int n_in,
                              void* d_out, int out_size, void* d_ws, size_t ws_size,
                              hipStream_t stream) {
    const float* z      = (const float*)d_in[0];
    const float* zf     = (const float*)d_in[1];
    const float* coil_r = (const float*)d_in[2];
    const float* coil_i = (const float*)d_in[3];
    const int*   maskp  = (const int*)d_in[4];
    const float* miu    = (const float*)d_in[5];
    float* out = (float*)d_out;

    char* w = (char*)d_ws;
    size_t off = 0;
    auto carve = [&](size_t bytes) -> void* {
        void* ptr = w + off;
        off += (bytes + 511) & ~(size_t)511;
        return ptr;
    };
    float2* P0    = (float2*)carve((size_t)DHWn * 8);
    float2* P1    = (float2*)carve((size_t)DHWn * 8);
    float2* R     = (float2*)carve((size_t)DHWn * 8);
    float2* Bv    = (float2*)carve((size_t)DHWn * 8);
    float2* COIL  = (float2*)carve((size_t)Cn * HWn * 8);
    float*  MASKP = (float*)carve((size_t)HWn * 4);
    float2* TWS   = (float2*)carve(TW_NT * 8);
    double* S     = (double*)carve(64 * 8);

    size_t imgSet = (size_t)DHWn * 8;   // one coil-slot (12 slices), 9.63 MB
    // (coils staged per chunk, z-splits of the combine); NZ divides cc.
    int cc = 1, NZ = 1;
    {
        const int cand[6][2] = {{10,2},{10,1},{5,1},{2,1},{1,1},{1,1}};
        for (int i = 0; i < 6; ++i) {
            size_t need = off + (size_t)(cand[i][0] + cand[i][1]) * imgSet;
            if (need <= ws_size) { cc = cand[i][0]; NZ = cand[i][1]; break; }
        }
    }
    float2* Qp  = (float2*)carve((size_t)NZ * imgSet);   // NZ partial-q buffers
    float2* Y1T = (float2*)carve((size_t)cc * imgSet);   // staged slices [c][d][oct][h][l8]
    int nch = Cn / cc;
    int ccz = cc / NZ;

    k_init_misc<<<1, 1024, 0, stream>>>(TWS, S);
    k_build_p<<<1024, 256, 0, stream>>>(z, zf, miu, P0, R, Bv, S);
    k_build_coil<<<1024, 256, 0, stream>>>(coil_r, coil_i, COIL);
    k_build_mask<<<512, 256, 0, stream>>>(maskp, MASKP);

    for (int it = 0; it < 5; ++it) {
        float2* Pcur = (it & 1) ? P1 : P0;     // p for this iteration
        float2* Pold = (it & 1) ? P0 : P1;     // previous p (read source for it>=1)
        const float2* Pread = (it == 0) ? Pcur : Pold;
        for (int ch = 0; ch < nch; ++ch) {
            int cs = ch * cc;
            dim3 gf(Hn / 8, Dn, cc);    // 56 x 12 x cc
            dim3 gc(28, 24, cc);        // octet x (d + 12*half) x cc
            dim3 gi(Hn / 8, Dn, NZ);    // 56 x 12 x NZ, each z does cc/NZ coils
            k_rowfft0<<<gf, 256, 0, stream>>>(Pread, R, Pcur, COIL, Y1T, TWS, S, cs, it);
            k_colfft<<<gc, 256, 0, stream>>>(Y1T, MASKP, TWS);
            k_irow_combine<<<gi, 256, 0, stream>>>(Y1T, COIL, Pcur, Qp, miu, S, TWS,
                                                   ccz, cs, ch == 0 ? 1 : 0,
                                                   ch == nch - 1 ? 1 : 0, it);
        }
        k_update_br<<<1024, 256, 0, stream>>>(S, S, it, (const float4*)Pcur, (const float4*)Qp,
                                              NZ, (float4*)Bv, (float4*)R);
    }
    k_output<<<1024, 256, 0, stream>>>(Bv, out);
}

// Round 15
// 1026.922 us; speedup vs baseline: 1.0933x; 1.0536x over previous
//
#include <hip/hip_runtime.h>
#include <math.h>

// Problem constants (fixed shapes from setup_inputs)
#define Dn   12
#define Hn   448
#define Wn   224
#define HWn  (Hn*Wn)        // 100352
#define DHWn (Dn*HWn)       // 1204224
#define Cn   10

// Y1T layout is OCTET-BLOCKED per slice (c,d): element (L, h) stored at
//   (L>>3)*3584 + h*8 + (L&7)        (3584 = 448*8; octet = 28 KB contiguous)
// where L is the bit-rev-permuted line index (identity L = d7*32+l32).
// - colfft: one block per HALF-octet (4 lines); the two halves of an octet are
//   placed 336 bids apart (= 0 mod 8) so they land on the SAME XCD and share L2.
// - rowfft stores / irow loads: per d7, 64-B segments; adjacent-row half-waves
//   complete each 128-B cache line -> no over-fetch.
#define OCT_F2 3584

// Twiddle table (float2 in global):
#define TW_W32   0     // 16:  W32^j
#define TW_W7    16    // 7:   W7^j (unused by Winograd path, kept for layout)
#define TW_W64   23    // 32:  W64^j
#define TW_T224  55    // 224: W224^{d7*l32}  [d7*32+l32]
#define TW_T448  279   // 448: W448^{d7*lane} [d7*64+lane]
#define TW_NT    727

// ---------- complex helpers ----------
__device__ __forceinline__ float2 cmul(float2 a, float2 b) {
    return make_float2(fmaf(a.x, b.x, -a.y * b.y), fmaf(a.x, b.y, a.y * b.x));
}
__device__ __forceinline__ float2 cfma(float2 a, float2 b, float2 acc) {
    acc.x = fmaf(a.x, b.x, fmaf(-a.y, b.y, acc.x));
    acc.y = fmaf(a.x, b.y, fmaf(a.y, b.x, acc.y));
    return acc;
}
__device__ __forceinline__ float2 cadd(float2 a, float2 b) { return make_float2(a.x + b.x, a.y + b.y); }
__device__ __forceinline__ float2 csub(float2 a, float2 b) { return make_float2(a.x - b.x, a.y - b.y); }
__host__ __device__ constexpr int brev5(int i) {
    return ((i & 1) << 4) | ((i & 2) << 2) | (i & 4) | ((i & 8) >> 2) | ((i & 16) >> 4);
}

__device__ __forceinline__ float2 shflx2(float2 v, int m) {
    return make_float2(__shfl_xor(v.x, m, 64), __shfl_xor(v.y, m, 64));
}

// DPP quad_perm lane exchange (VALU pipe, not LDS): xor-1 = [1,0,3,2] = 0xB1,
// xor-2 = [2,3,0,1] = 0x4E. All lanes active at every call site.
template<int CTRL>
__device__ __forceinline__ float dppmov(float x) {
    return __int_as_float(__builtin_amdgcn_update_dpp(
        0, __float_as_int(x), CTRL, 0xF, 0xF, true));
}
// lane exchange by xor(dist); dist is a compile-time constant after unroll ->
// folds to DPP (dist 1,2) or ds_swizzle (dist >= 4).
__device__ __forceinline__ float2 xgroup(float2 v, int dist) {
    if (dist == 1) return make_float2(dppmov<0xB1>(v.x), dppmov<0xB1>(v.y));
    if (dist == 2) return make_float2(dppmov<0x4E>(v.x), dppmov<0x4E>(v.y));
    return shflx2(v, dist);
}

// v_permlane32_swap_b32 (VALU pipe, not LDS): swaps a.hi with b.lo ->
// returns a'={a.lo, b.lo}, b'={a.hi, b.hi}.
typedef unsigned int uv2 __attribute__((ext_vector_type(2)));
__device__ __forceinline__ void swap32f(float &a, float &b) {
    uv2 r = __builtin_amdgcn_permlane32_swap(__float_as_uint(a), __float_as_uint(b), false, false);
    a = __uint_as_float(r.x);
    b = __uint_as_float(r.y);
}

__device__ __forceinline__ double waveReduce(double v) {
#pragma unroll
    for (int o = 32; o > 0; o >>= 1) v += __shfl_down(v, o, 64);
    return v;
}

// ---------- Winograd-style DFT-7 (66 VALU ops vs 168 naive) ----------
// Forward (SGN=+1): y[k] = Sum_n x[n] exp(-2*pi*i*n*k/7) = A_k - i*B_k
// Inverse (SGN=-1): conj twiddles -> y[k] = A_k + i*B_k
template<int SGN>
__device__ __forceinline__ void dft7(const float2* __restrict__ x, float2* __restrict__ y) {
    const float c1 =  0.62348980185873359f;   // cos(2pi/7)
    const float c2 = -0.22252093395631445f;   // cos(4pi/7)
    const float c3 = -0.90096886790241915f;   // cos(6pi/7)
    const float s1 =  0.78183148246802980f;   // sin(2pi/7)
    const float s2 =  0.97492791218182362f;   // sin(4pi/7)
    const float s3 =  0.43388373911755823f;   // sin(6pi/7)
    float2 u1 = cadd(x[1], x[6]), v1 = csub(x[1], x[6]);
    float2 u2 = cadd(x[2], x[5]), v2 = csub(x[2], x[5]);
    float2 u3 = cadd(x[3], x[4]), v3 = csub(x[3], x[4]);
    y[0] = make_float2(x[0].x + u1.x + u2.x + u3.x,
                       x[0].y + u1.y + u2.y + u3.y);
    float2 A1, A2, A3, B1, B2, B3;
    A1.x = fmaf(c1, u1.x, fmaf(c2, u2.x, fmaf(c3, u3.x, x[0].x)));
    A1.y = fmaf(c1, u1.y, fmaf(c2, u2.y, fmaf(c3, u3.y, x[0].y)));
    A2.x = fmaf(c2, u1.x, fmaf(c3, u2.x, fmaf(c1, u3.x, x[0].x)));
    A2.y = fmaf(c2, u1.y, fmaf(c3, u2.y, fmaf(c1, u3.y, x[0].y)));
    A3.x = fmaf(c3, u1.x, fmaf(c1, u2.x, fmaf(c2, u3.x, x[0].x)));
    A3.y = fmaf(c3, u1.y, fmaf(c1, u2.y, fmaf(c2, u3.y, x[0].y)));
    B1.x = fmaf(s1, v1.x, fmaf(s2, v2.x,  s3 * v3.x));
    B1.y = fmaf(s1, v1.y, fmaf(s2, v2.y,  s3 * v3.y));
    B2.x = fmaf(s2, v1.x, fmaf(-s3, v2.x, -s1 * v3.x));
    B2.y = fmaf(s2, v1.y, fmaf(-s3, v2.y, -s1 * v3.y));
    B3.x = fmaf(s3, v1.x, fmaf(-s1, v2.x,  s2 * v3.x));
    B3.y = fmaf(s3, v1.y, fmaf(-s1, v2.y,  s2 * v3.y));
    if (SGN > 0) {
        y[1] = make_float2(A1.x + B1.y, A1.y - B1.x);
        y[6] = make_float2(A1.x - B1.y, A1.y + B1.x);
        y[2] = make_float2(A2.x + B2.y, A2.y - B2.x);
        y[5] = make_float2(A2.x - B2.y, A2.y + B2.x);
        y[3] = make_float2(A3.x + B3.y, A3.y - B3.x);
        y[4] = make_float2(A3.x - B3.y, A3.y + B3.x);
    } else {
        y[1] = make_float2(A1.x - B1.y, A1.y + B1.x);
        y[6] = make_float2(A1.x + B1.y, A1.y - B1.x);
        y[2] = make_float2(A2.x - B2.y, A2.y + B2.x);
        y[5] = make_float2(A2.x + B2.y, A2.y - B2.x);
        y[3] = make_float2(A3.x - B3.y, A3.y + B3.x);
        y[4] = make_float2(A3.x + B3.y, A3.y - B3.x);
    }
}

// ---------- init kernels ----------
__global__ void k_init_misc(float2* __restrict__ tws, double* __restrict__ S) {
    int t = threadIdx.x;  // 1024 threads
    const double PI2 = 6.283185307179586476925287;
    if (t < 16)              { double s, c; sincos(-(PI2 * t) / 32.0, &s, &c); tws[TW_W32 + t] = make_float2((float)c, (float)s); }
    if (t >= 16 && t < 23)   { int j = t - 16; double s, c; sincos(-(PI2 * j) / 7.0,  &s, &c); tws[TW_W7 + j]  = make_float2((float)c, (float)s); }
    if (t >= 23 && t < 55)   { int j = t - 23; double s, c; sincos(-(PI2 * j) / 64.0, &s, &c); tws[TW_W64 + j] = make_float2((float)c, (float)s); }
    if (t >= 55 && t < 279)  { int j = t - 55;  int d7 = j >> 5, l = j & 31;
                               double s, c; sincos(-(PI2 * (d7 * l)) / 224.0, &s, &c);
                               tws[TW_T224 + j] = make_float2((float)c, (float)s); }
    if (t >= 279 && t < 727) { int j = t - 279; int d7 = j >> 6, l = j & 63;
                               double s, c; sincos(-(PI2 * (d7 * l)) / 448.0, &s, &c);
                               tws[TW_T448 + j] = make_float2((float)c, (float)s); }
    if (t >= 727 && t < 759) S[t - 727] = 0.0;
}

__global__ void k_build_p(const float* __restrict__ z, const float* __restrict__ zf,
                          const float* __restrict__ miu,
                          float2* __restrict__ p, float2* __restrict__ r, float2* __restrict__ b,
                          double* __restrict__ S) {
    float mu = fabsf(miu[0]);
    double acc = 0.0;
    for (int e = blockIdx.x * blockDim.x + threadIdx.x; e < DHWn; e += gridDim.x * blockDim.x) {
        int d = e / HWn, rem = e - d * HWn;
        int h = rem / Wn, w = rem - h * Wn;
        int hs = h + Hn / 2; if (hs >= Hn) hs -= Hn;
        int ws = w + Wn / 2; if (ws >= Wn) ws -= Wn;
        int src = d * HWn + hs * Wn + ws;
        float pr = fmaf(mu, z[src], zf[src]);
        float pi = fmaf(mu, z[DHWn + src], zf[DHWn + src]);
        float2 v = make_float2(pr, pi);
        p[e] = v; r[e] = v; b[e] = make_float2(0.f, 0.f);
        acc += (double)pr * pr + (double)pi * pi;
    }
    acc = waveReduce(acc);
    if ((threadIdx.x & 63) == 0) atomicAdd(&S[0], acc);
}

__global__ void k_build_coil(const float* __restrict__ cr, const float* __restrict__ ci,
                             float2* __restrict__ coil) {
    for (int e = blockIdx.x * blockDim.x + threadIdx.x; e < Cn * HWn; e += gridDim.x * blockDim.x) {
        int c = e / HWn, rem = e - c * HWn;
        int h = rem / Wn, w = rem - h * Wn;
        int hs = h + Hn / 2; if (hs >= Hn) hs -= Hn;
        int ws = w + Wn / 2; if (ws >= Wn) ws -= Wn;
        int src = c * HWn + hs * Wn + ws;
        coil[e] = make_float2(cr[src], ci[src]);
    }
}

// permuted + shifted + scaled mask: maskP[L*448 + h], line L holds true
// frequency column w(L) = 7*brev5(L&31) + (L>>5)
__global__ void k_build_mask(const int* __restrict__ mask, float* __restrict__ maskP) {
    for (int e = blockIdx.x * blockDim.x + threadIdx.x; e < HWn; e += gridDim.x * blockDim.x) {
        int L = e / Hn, h = e - L * Hn;
        int w = 7 * brev5(L & 31) + (L >> 5);
        int hs = h + Hn / 2; if (hs >= Hn) hs -= Hn;
        int ws = w + Wn / 2; if (ws >= Wn) ws -= Wn;
        maskP[e] = (float)mask[hs * Wn + ws] * (1.0f / (float)HWn);
    }
}

// ---------- forward row FFT (224 = 7*32 lane-FFT), coil-mul, direct octet store ----------
// No LDS, no barriers. FUSED update_p: for it>=1, p = r + beta*p_old on the fly;
// global-coil-0 block stores p into Pnew (ping-pong, no races).
__global__ __launch_bounds__(256) void k_rowfft0(const float2* __restrict__ Pread,
                                                 const float2* __restrict__ Rv,
                                                 float2* __restrict__ Pnew,
                                                 const float2* __restrict__ coil,
                                                 float2* __restrict__ Y1T,
                                                 const float2* __restrict__ twg,
                                                 const double* __restrict__ S,
                                                 int chunkStart, int it) {
    int tid = threadIdx.x;
    int lane = tid & 63, wv = tid >> 6, hi = lane >> 5, l32 = lane & 31;
    int h0 = blockIdx.x * 8, d = blockIdx.y, cz = blockIdx.z;
    int row = h0 + 2 * wv + hi;
    const float2* w32g = twg + TW_W32;
    const float2* t224 = twg + TW_T224;

    size_t roff = (size_t)d * HWn + (size_t)row * Wn;
    const float2* prow = Pread + roff;
    const float2* crow = coil + (size_t)(chunkStart + cz) * HWn + (size_t)row * Wn;

    float2 pv[7];
    if (it == 0) {
#pragma unroll
        for (int b = 0; b < 7; ++b) pv[b] = prow[32 * b + l32];
    } else {
        float beta = (float)(S[it] / S[it - 1]);
        const float2* rrow = Rv + roff;
#pragma unroll
        for (int b = 0; b < 7; ++b) {
            float2 rv = rrow[32 * b + l32];
            float2 po = prow[32 * b + l32];
            pv[b] = make_float2(fmaf(beta, po.x, rv.x), fmaf(beta, po.y, rv.y));
        }
        if (chunkStart + cz == 0) {
            float2* pw = Pnew + roff;
#pragma unroll
            for (int b = 0; b < 7; ++b) pw[32 * b + l32] = pv[b];
        }
    }

    float2 xb[7];
#pragma unroll
    for (int b = 0; b < 7; ++b) xb[b] = cmul(pv[b], crow[32 * b + l32]);

    // DFT7 (Winograd)
    float2 y[7];
    dft7<1>(xb, y);
    // twiddle W224^{l32*d7} from table
#pragma unroll
    for (int d7 = 1; d7 < 7; ++d7) y[d7] = cmul(y[d7], t224[d7 * 32 + l32]);

    // FFT32 across each half-wave, DIF (sign-trick form: y' = (t + s*y)*weff)
#pragma unroll
    for (int s = 0; s < 5; ++s) {
        int dist = 16 >> s;
        float2 wst = w32g[(l32 & (dist - 1)) << s];
        bool h2 = (l32 & dist) != 0;
        float sg = h2 ? -1.f : 1.f;
        float2 weff = h2 ? wst : make_float2(1.f, 0.f);
#pragma unroll
        for (int d7 = 0; d7 < 7; ++d7) {
            float2 t = xgroup(y[d7], dist);
            float2 u = make_float2(fmaf(sg, y[d7].x, t.x), fmaf(sg, y[d7].y, t.y));
            y[d7] = cmul(u, weff);
        }
    }

    // direct store: line L = d7*32+l32 -> octet (L>>3), slot (L&7)
    float2* ybase = Y1T + ((size_t)cz * Dn + d) * (size_t)HWn;
    int oct0 = l32 >> 3, l8 = l32 & 7;
#pragma unroll
    for (int d7 = 0; d7 < 7; ++d7)
        ybase[(size_t)(4 * d7 + oct0) * OCT_F2 + (size_t)row * 8 + l8] = y[d7];
}

// ---------- column FFT448 + mask + IFFT448 ----------
// 256 threads = 4 waves; one block per HALF-octet (4 lines, 1 line/wave).
// dist-32 exchanges: v_permlane32_swap (VALU). dist-1/2: DPP quad_perm (VALU).
// Only dist 4/8/16 remain on the LDS pipe (ds_swizzle).
#define CP 452
__global__ __launch_bounds__(256) void k_colfft(float2* __restrict__ Y1T,
                                                const float* __restrict__ maskP,
                                                const float2* __restrict__ twg) {
    __shared__ float2 ls[4][CP];
    int tid = threadIdx.x;               // 0..255
    int lane = tid & 63, wv = tid >> 6;  // 4 waves
    int oct = blockIdx.x;                // 28
    int byy = blockIdx.y;                // 24 = d + 12*half
    int d = (byy < 12) ? byy : byy - 12;
    int half = (byy < 12) ? 0 : 1;
    int cz = blockIdx.z;
    const float2* w64t = twg + TW_W64;
    const float2* t448 = twg + TW_T448;

    float2* base = Y1T + ((size_t)cz * Dn + d) * (size_t)HWn + (size_t)oct * OCT_F2
                 + 4 * half;             // slots 4*half .. 4*half+3

    // stage in: 448 h x 4 slots = 1792 f2 = 896 f4 (two f4 per h)
#pragma unroll
    for (int m = 0; m < 4; ++m) {
        int j4 = tid + m * 256;
        if (j4 < 896) {
            int h = j4 >> 1, q = j4 & 1;     // f4 covers local slots 2q, 2q+1 at col h
            float4 v = *(const float4*)&base[(size_t)h * 8 + 2 * q];
            ls[2 * q][h]     = make_float2(v.x, v.y);
            ls[2 * q + 1][h] = make_float2(v.z, v.w);
        }
    }
    __syncthreads();

    int L = oct * 8 + 4 * half + wv;     // this wave's line

    float2 xb[7];
#pragma unroll
    for (int b = 0; b < 7; ++b) xb[b] = ls[wv][64 * b + lane];

    // twiddles W448^{lane*d7} (reused conjugated in the inverse pass)
    float2 tp[7];
#pragma unroll
    for (int d7 = 1; d7 < 7; ++d7) tp[d7] = t448[d7 * 64 + lane];

    // forward DFT7 (Winograd) + W448 twiddle
    float2 y[7];
    dft7<1>(xb, y);
#pragma unroll
    for (int d7 = 1; d7 < 7; ++d7) y[d7] = cmul(y[d7], tp[d7]);

    // ---- forward FFT64, stage dist=32 ----
    // pairs (0,1),(2,3),(4,5): permlane-packed. After this, reg 2p holds the
    // sum/even subtree {u_even | v_even} and reg 2p+1 the dif/odd subtree.
    {
        float2 wst = w64t[lane & 31];
#pragma unroll
        for (int p = 0; p < 3; ++p) {
            float2 u = y[2 * p], v = y[2 * p + 1];
            swap32f(u.x, v.x); swap32f(u.y, v.y);    // u={lo_u,lo_v}, v={hi_u,hi_v}
            y[2 * p]     = cadd(u, v);               // S (no twiddle)
            y[2 * p + 1] = cmul(csub(u, v), wst);    // D * w
        }
        // y[6] classic
        bool hb = lane >= 32;
        float sg = hb ? -1.f : 1.f;
        float2 weff = hb ? wst : make_float2(1.f, 0.f);
        float2 t = shflx2(y[6], 32);
        float2 u6 = make_float2(fmaf(sg, y[6].x, t.x), fmaf(sg, y[6].y, t.y));
        y[6] = cmul(u6, weff);
    }
    // stages dist=16..1 (within 32-halves; identical for packed regs)
#pragma unroll
    for (int s = 1; s < 6; ++s) {
        int dist = 32 >> s;
        float2 wst = w64t[(lane & (dist - 1)) << s];
        bool hb = (lane & dist) != 0;
        float sg = hb ? -1.f : 1.f;
        float2 weff = hb ? wst : make_float2(1.f, 0.f);
#pragma unroll
        for (int d7 = 0; d7 < 7; ++d7) {
            float2 t = xgroup(y[d7], dist);
            float2 u = make_float2(fmaf(sg, y[d7].x, t.x), fmaf(sg, y[d7].y, t.y));
            y[d7] = cmul(u, weff);
        }
    }

    // mask. Unpacked H-freq index: 7*(brev5(lane&31)<<1 | (lane>>5)) + d7.
    // Packed regs: subtree bit is 0 for S-regs (2p), 1 for D-regs (2p+1);
    // d7 = 2p for lanes<32 (u), 2p+1 for lanes>=32 (v).
    {
        int rb0 = brev5(lane & 31) << 1;
        const float* mbase = maskP + (size_t)L * Hn;
        bool lo = lane < 32;
#pragma unroll
        for (int p = 0; p < 3; ++p) {
            int dsel = lo ? (2 * p) : (2 * p + 1);
            float mS = mbase[7 * rb0 + dsel];
            float mD = mbase[7 * (rb0 + 1) + dsel];
            y[2 * p].x *= mS;     y[2 * p].y *= mS;
            y[2 * p + 1].x *= mD; y[2 * p + 1].y *= mD;
        }
        int rb6 = rb0 | (lane >> 5);
        float m6 = mbase[7 * rb6 + 6];
        y[6].x *= m6; y[6].y *= m6;
    }

    // inverse FFT64, DIT stages dist=1..16 (within halves; packed-safe)
#pragma unroll
    for (int s = 0; s < 5; ++s) {
        int dist = 1 << s;
        float2 wst = w64t[(lane & (dist - 1)) << (5 - s)];
        wst.y = -wst.y;
        bool hb = (lane & dist) != 0;
        float2 c = hb ? make_float2(-wst.x, -wst.y) : wst;
#pragma unroll
        for (int d7 = 0; d7 < 7; ++d7) {
            float2 t = xgroup(y[d7], dist);
            float2 B = hb ? y[d7] : t;
            float2 A = hb ? t : y[d7];
            y[d7] = cfma(c, B, A);
        }
    }
    // ---- final inverse stage dist=32 ----
    {
        float2 wst = w64t[lane & 31];
        float2 cw  = make_float2(wst.x, -wst.y);    // conj
        float2 ncw = make_float2(-cw.x, -cw.y);
#pragma unroll
        for (int p = 0; p < 3; ++p) {
            float2 S = y[2 * p], D = y[2 * p + 1];  // S={u_e,v_e}, D={u_o,v_o}
            float2 T1 = cfma(cw,  D, S);            // even + cw*odd  -> out.lo
            float2 T2 = cfma(ncw, D, S);            // even - cw*odd  -> out.hi
            swap32f(T1.x, T2.x); swap32f(T1.y, T2.y);  // -> (u_out, v_out)
            y[2 * p] = T1; y[2 * p + 1] = T2;
        }
        // y[6] classic
        bool hb = lane >= 32;
        float2 c = hb ? ncw : cw;
        float2 t = shflx2(y[6], 32);
        float2 B = hb ? y[6] : t;
        float2 A = hb ? t : y[6];
        y[6] = cfma(c, B, A);
    }

    // conj W448 twiddle + inverse DFT7 (Winograd) + LDS writeback
#pragma unroll
    for (int d7 = 1; d7 < 7; ++d7) {
        float2 c = make_float2(tp[d7].x, -tp[d7].y);
        y[d7] = cmul(y[d7], c);
    }
    dft7<-1>(y, xb);
#pragma unroll
    for (int b = 0; b < 7; ++b) ls[wv][64 * b + lane] = xb[b];
    __syncthreads();

    // stage out: mirror of stage in
#pragma unroll
    for (int m = 0; m < 4; ++m) {
        int j4 = tid + m * 256;
        if (j4 < 896) {
            int h = j4 >> 1, q = j4 & 1;
            float2 a = ls[2 * q][h];
            float2 b = ls[2 * q + 1][h];
            *(float4*)&base[(size_t)h * 8 + 2 * q] = make_float4(a.x, a.y, b.x, b.y);
        }
    }
}

// ---------- fused inverse row FFT + conj-coil + coil-sum + q/dot epilogue ----------
// Octet layout: each half-wave loads its 7 DIT-ready line-groups directly into
// registers. NO LDS staging, NO barriers in the coil loop.
// Coil loop split over gridDim.z into partial Qp[zid]; dots are linear in q.
__global__ __launch_bounds__(256) void k_irow_combine(const float2* __restrict__ Y1T,
                                                      const float2* __restrict__ coil,
                                                      const float2* __restrict__ P,
                                                      float2* __restrict__ Qp,
                                                      const float* __restrict__ miu,
                                                      double* __restrict__ S,
                                                      const float2* __restrict__ twg,
                                                      int ccz, int chunkStart,
                                                      int first, int last, int it) {
    __shared__ double sred[8];
    int tid = threadIdx.x;
    int lane = tid & 63, wv = tid >> 6, hi = lane >> 5, l32 = lane & 31;
    int h0 = blockIdx.x * 8, d = blockIdx.y;
    int zid = blockIdx.z;
    int zbase = zid * ccz;
    float2* Q = Qp + (size_t)zid * DHWn;
    int row = h0 + 2 * wv + hi;
    const float2* w32g = twg + TW_W32;
    const float2* t224 = twg + TW_T224;

    float2 tp[7];
#pragma unroll
    for (int d7 = 1; d7 < 7; ++d7) {
        float2 v = t224[d7 * 32 + l32];
        tp[d7] = make_float2(v.x, -v.y);   // conj (inverse twiddle)
    }

    float2 acc[7];
#pragma unroll
    for (int b = 0; b < 7; ++b) acc[b] = make_float2(0.f, 0.f);

    int oct0 = l32 >> 3, l8 = l32 & 7;
    for (int cz = 0; cz < ccz; ++cz) {
        const float2* ybase = Y1T + ((size_t)(zbase + cz) * Dn + d) * (size_t)HWn;
        const float2* crow = coil + (size_t)(chunkStart + zbase + cz) * HWn + (size_t)row * Wn;

        // DIT-ready register loads: y[d7] = line (d7*32+l32) at this row
        float2 y[7];
#pragma unroll
        for (int d7 = 0; d7 < 7; ++d7)
            y[d7] = ybase[(size_t)(4 * d7 + oct0) * OCT_F2 + (size_t)row * 8 + l8];
        float2 cpre[7];
#pragma unroll
        for (int b = 0; b < 7; ++b) cpre[b] = crow[32 * b + l32];

        // inverse FFT32 across half-wave, DIT (sign-trick): y' = A + c*B
#pragma unroll
        for (int s = 0; s < 5; ++s) {
            int dist = 1 << s;
            float2 wst = w32g[(l32 & (dist - 1)) << (4 - s)];
            wst.y = -wst.y;
            bool h2 = (l32 & dist) != 0;
            float2 c = h2 ? make_float2(-wst.x, -wst.y) : wst;
#pragma unroll
            for (int d7 = 0; d7 < 7; ++d7) {
                float2 t = xgroup(y[d7], dist);
                float2 B = h2 ? y[d7] : t;
                float2 A = h2 ? t : y[d7];
                y[d7] = cfma(c, B, A);
            }
        }
        // conj twiddle W224^{-l32*d7}
#pragma unroll
        for (int d7 = 1; d7 < 7; ++d7) y[d7] = cmul(y[d7], tp[d7]);
        // inverse DFT7 (Winograd) + conj-coil accumulate
        float2 s7[7];
        dft7<-1>(y, s7);
#pragma unroll
        for (int b = 0; b < 7; ++b) {
            float2 s = s7[b];
            float2 c = cpre[b];
            acc[b].x += fmaf(s.x, c.x, s.y * c.y);
            acc[b].y += fmaf(s.y, c.x, -s.x * c.y);
        }
    }

    // epilogue: partial q; only zid==0 folds in mu*p (exactly once in the sum).
    float mu = fabsf(miu[0]);
    const float2* prow = P + (size_t)d * HWn + (size_t)row * Wn;
    float2* qrow = Q + (size_t)d * HWn + (size_t)row * Wn;
    double ar = 0.0, ai = 0.0;
#pragma unroll
    for (int b = 0; b < 7; ++b) {
        float2 pv = prow[32 * b + l32];
        float2 s0;
        if (first) {
            if (zid == 0) s0 = make_float2(fmaf(mu, pv.x, acc[b].x), fmaf(mu, pv.y, acc[b].y));
            else          s0 = acc[b];
        } else {
            float2 qv = qrow[32 * b + l32];
            s0 = cadd(qv, acc[b]);
        }
        qrow[32 * b + l32] = s0;
        if (last) {
            ar += (double)(s0.x * pv.x + s0.y * pv.y);
            ai += (double)(s0.y * pv.x - s0.x * pv.y);
        }
    }
    if (last) {
        ar = waveReduce(ar);
        ai = waveReduce(ai);
        if (lane == 0) { sred[wv] = ar; sred[4 + wv] = ai; }
        __syncthreads();
        if (tid == 0) {
            atomicAdd(&S[8 + it],  sred[0] + sred[1] + sred[2] + sred[3]);
            atomicAdd(&S[16 + it], sred[4] + sred[5] + sred[6] + sred[7]);
        }
    }
}

// ---------- CG scalar update (float4 = 2 complex per lane) ----------
// q points at nz partial buffers, each N2 float4s; summed inline.
// (update_p is fused into the next iteration's k_rowfft0.)
__global__ void k_update_br(const double* __restrict__ Sin, double* __restrict__ S, int it,
                            const float4* __restrict__ p, const float4* __restrict__ q,
                            int nz,
                            float4* __restrict__ b, float4* __restrict__ r) {
    double rr = Sin[it], qr = Sin[8 + it], qi = Sin[16 + it];
    double den = qr * qr + qi * qi;
    float arf = (float)(rr * qr / den);
    float aif = (float)(-rr * qi / den);
    double acc = 0.0;
    const int N2 = DHWn / 2;
    for (int e = blockIdx.x * blockDim.x + threadIdx.x; e < N2; e += gridDim.x * blockDim.x) {
        float4 pv = p[e], bv = b[e], rv = r[e];
        float4 qv = q[e];
        for (int z = 1; z < nz; ++z) {
            float4 t = q[(size_t)z * N2 + e];
            qv.x += t.x; qv.y += t.y; qv.z += t.z; qv.w += t.w;
        }
        bv.x += arf * pv.x - aif * pv.y;  bv.y += arf * pv.y + aif * pv.x;
        bv.z += arf * pv.z - aif * pv.w;  bv.w += arf * pv.w + aif * pv.z;
        b[e] = bv;
        rv.x -= arf * qv.x - aif * qv.y;  rv.y -= arf * qv.y + aif * qv.x;
        rv.z -= arf * qv.z - aif * qv.w;  rv.w -= arf * qv.w + aif * qv.z;
        r[e] = rv;
        acc += (double)rv.x * rv.x + (double)rv.y * rv.y
             + (double)rv.z * rv.z + (double)rv.w * rv.w;
    }
    acc = waveReduce(acc);
    if ((threadIdx.x & 63) == 0) atomicAdd(&S[it + 1], acc);
}

__global__ void k_output(const float2* __restrict__ b, float* __restrict__ out) {
    for (int e = blockIdx.x * blockDim.x + threadIdx.x; e < DHWn; e += gridDim.x * blockDim.x) {
        int d = e / HWn, rem = e - d * HWn;
        int h = rem / Wn, w = rem - h * Wn;
        int hs = h + Hn / 2; if (hs >= Hn) hs -= Hn;
        int ws = w + Wn / 2; if (ws >= Wn) ws -= Wn;
        float2 v = b[d * HWn + hs * Wn + ws];
        out[e] = v.x;
        out[DHWn + e] = v.y;
    }
}

extern "C" void kernel_launch(void* const* d_in, const int* in_sizes, int n_in,
                              void* d_out, int out_size, void* d_ws, size_t ws_size,
                              hipStream_t stream) {
    const float* z      = (const float*)d_in[0];
    const float* zf     = (const float*)d_in[1];
    const float* coil_r = (const float*)d_in[2];
    const float* coil_i = (const float*)d_in[3];
    const int*   maskp  = (const int*)d_in[4];
    const float* miu    = (const float*)d_in[5];
    float* out = (float*)d_out;

    char* w = (char*)d_ws;
    size_t off = 0;
    auto carve = [&](size_t bytes) -> void* {
        void* ptr = w + off;
        off += (bytes + 511) & ~(size_t)511;
        return ptr;
    };
    float2* P0    = (float2*)carve((size_t)DHWn * 8);
    float2* P1    = (float2*)carve((size_t)DHWn * 8);
    float2* R     = (float2*)carve((size_t)DHWn * 8);
    float2* Bv    = (float2*)carve((size_t)DHWn * 8);
    float2* COIL  = (float2*)carve((size_t)Cn * HWn * 8);
    float*  MASKP = (float*)carve((size_t)HWn * 4);
    float2* TWS   = (float2*)carve(TW_NT * 8);
    double* S     = (double*)carve(64 * 8);

    size_t imgSet = (size_t)DHWn * 8;   // one coil-slot (12 slices), 9.63 MB
    // (coils staged per chunk, z-splits of the combine); NZ divides cc.
    int cc = 1, NZ = 1;
    {
        const int cand[6][2] = {{10,2},{10,1},{5,1},{2,1},{1,1},{1,1}};
        for (int i = 0; i < 6; ++i) {
            size_t need = off + (size_t)(cand[i][0] + cand[i][1]) * imgSet;
            if (need <= ws_size) { cc = cand[i][0]; NZ = cand[i][1]; break; }
        }
    }
    float2* Qp  = (float2*)carve((size_t)NZ * imgSet);   // NZ partial-q buffers
    float2* Y1T = (float2*)carve((size_t)cc * imgSet);   // staged slices [c][d][oct][h][l8]
    int nch = Cn / cc;
    int ccz = cc / NZ;

    k_init_misc<<<1, 1024, 0, stream>>>(TWS, S);
    k_build_p<<<1024, 256, 0, stream>>>(z, zf, miu, P0, R, Bv, S);
    k_build_coil<<<1024, 256, 0, stream>>>(coil_r, coil_i, COIL);
    k_build_mask<<<512, 256, 0, stream>>>(maskp, MASKP);

    for (int it = 0; it < 5; ++it) {
        float2* Pcur = (it & 1) ? P1 : P0;     // p for this iteration
        float2* Pold = (it & 1) ? P0 : P1;     // previous p (read source for it>=1)
        const float2* Pread = (it == 0) ? Pcur : Pold;
        for (int ch = 0; ch < nch; ++ch) {
            int cs = ch * cc;
            dim3 gf(Hn / 8, Dn, cc);    // 56 x 12 x cc
            dim3 gc(28, 24, cc);        // octet x (d + 12*half) x cc
            dim3 gi(Hn / 8, Dn, NZ);    // 56 x 12 x NZ, each z does cc/NZ coils
            k_rowfft0<<<gf, 256, 0, stream>>>(Pread, R, Pcur, COIL, Y1T, TWS, S, cs, it);
            k_colfft<<<gc, 256, 0, stream>>>(Y1T, MASKP, TWS);
            k_irow_combine<<<gi, 256, 0, stream>>>(Y1T, COIL, Pcur, Qp, miu, S, TWS,
                                                   ccz, cs, ch == 0 ? 1 : 0,
                                                   ch == nch - 1 ? 1 : 0, it);
        }
        k_update_br<<<1024, 256, 0, stream>>>(S, S, it, (const float4*)Pcur, (const float4*)Qp,
                                              NZ, (float4*)Bv, (float4*)R);
    }
    k_output<<<1024, 256, 0, stream>>>(Bv, out);
}

// Round 16
// 1016.313 us; speedup vs baseline: 1.1047x; 1.0104x over previous
//
#include <hip/hip_runtime.h>
#include <math.h>

// Problem constants (fixed shapes from setup_inputs)
#define Dn   12
#define Hn   448
#define Wn   224
#define HWn  (Hn*Wn)        // 100352
#define DHWn (Dn*HWn)       // 1204224
#define Cn   10

// Y1T layout is OCTET-BLOCKED per slice (c,d): element (L, h) stored at
//   (L>>3)*3584 + h*8 + (L&7)        (3584 = 448*8; octet = 28 KB contiguous)
// where L is the bit-rev-permuted line index (identity L = d7*32+l32).
// - colfft: one block per HALF-octet (4 lines); the two halves of an octet are
//   placed 336 bids apart (= 0 mod 8) so they land on the SAME XCD and share L2.
// - rowfft stores / irow loads: per d7, 64-B segments; adjacent-row half-waves
//   complete each 128-B cache line -> no over-fetch.
#define OCT_F2 3584

// Twiddle table (float2 in global):
#define TW_W32   0     // 16:  W32^j
#define TW_W7    16    // 7:   W7^j (unused by Winograd path, kept for layout)
#define TW_W64   23    // 32:  W64^j
#define TW_T224  55    // 224: W224^{d7*l32}  [d7*32+l32]
#define TW_T448  279   // 448: W448^{d7*lane} [d7*64+lane]
#define TW_NT    727

// ---------- complex helpers ----------
__device__ __forceinline__ float2 cmul(float2 a, float2 b) {
    return make_float2(fmaf(a.x, b.x, -a.y * b.y), fmaf(a.x, b.y, a.y * b.x));
}
__device__ __forceinline__ float2 cfma(float2 a, float2 b, float2 acc) {
    acc.x = fmaf(a.x, b.x, fmaf(-a.y, b.y, acc.x));
    acc.y = fmaf(a.x, b.y, fmaf(a.y, b.x, acc.y));
    return acc;
}
__device__ __forceinline__ float2 cadd(float2 a, float2 b) { return make_float2(a.x + b.x, a.y + b.y); }
__device__ __forceinline__ float2 csub(float2 a, float2 b) { return make_float2(a.x - b.x, a.y - b.y); }
__host__ __device__ constexpr int brev5(int i) {
    return ((i & 1) << 4) | ((i & 2) << 2) | (i & 4) | ((i & 8) >> 2) | ((i & 16) >> 4);
}

__device__ __forceinline__ float2 shflx2(float2 v, int m) {
    return make_float2(__shfl_xor(v.x, m, 64), __shfl_xor(v.y, m, 64));
}

// DPP lane exchanges (VALU pipe, not LDS):
//   xor-1 = quad_perm [1,0,3,2] = 0xB1; xor-2 = quad_perm [2,3,0,1] = 0x4E;
//   xor-8 = row_ror:8 = 0x128  ((i+8) mod 16 == i^8 within each 16-lane row).
template<int CTRL>
__device__ __forceinline__ float dppmov(float x) {
    return __int_as_float(__builtin_amdgcn_update_dpp(
        0, __float_as_int(x), CTRL, 0xF, 0xF, true));
}
// lane exchange by xor(dist); dist is compile-time after unroll ->
// folds to DPP (dist 1,2,8) or ds_swizzle (dist 4,16,32).
__device__ __forceinline__ float2 xgroup(float2 v, int dist) {
    if (dist == 1) return make_float2(dppmov<0xB1>(v.x),  dppmov<0xB1>(v.y));
    if (dist == 2) return make_float2(dppmov<0x4E>(v.x),  dppmov<0x4E>(v.y));
    if (dist == 8) return make_float2(dppmov<0x128>(v.x), dppmov<0x128>(v.y));
    return shflx2(v, dist);
}

// v_permlane32_swap_b32 (VALU pipe, not LDS): swaps a.hi with b.lo ->
// returns a'={a.lo, b.lo}, b'={a.hi, b.hi}.
typedef unsigned int uv2 __attribute__((ext_vector_type(2)));
__device__ __forceinline__ void swap32f(float &a, float &b) {
    uv2 r = __builtin_amdgcn_permlane32_swap(__float_as_uint(a), __float_as_uint(b), false, false);
    a = __uint_as_float(r.x);
    b = __uint_as_float(r.y);
}

__device__ __forceinline__ double waveReduce(double v) {
#pragma unroll
    for (int o = 32; o > 0; o >>= 1) v += __shfl_down(v, o, 64);
    return v;
}

// ---------- Winograd-style DFT-7 (66 VALU ops vs 168 naive) ----------
template<int SGN>
__device__ __forceinline__ void dft7(const float2* __restrict__ x, float2* __restrict__ y) {
    const float c1 =  0.62348980185873359f;   // cos(2pi/7)
    const float c2 = -0.22252093395631445f;   // cos(4pi/7)
    const float c3 = -0.90096886790241915f;   // cos(6pi/7)
    const float s1 =  0.78183148246802980f;   // sin(2pi/7)
    const float s2 =  0.97492791218182362f;   // sin(4pi/7)
    const float s3 =  0.43388373911755823f;   // sin(6pi/7)
    float2 u1 = cadd(x[1], x[6]), v1 = csub(x[1], x[6]);
    float2 u2 = cadd(x[2], x[5]), v2 = csub(x[2], x[5]);
    float2 u3 = cadd(x[3], x[4]), v3 = csub(x[3], x[4]);
    y[0] = make_float2(x[0].x + u1.x + u2.x + u3.x,
                       x[0].y + u1.y + u2.y + u3.y);
    float2 A1, A2, A3, B1, B2, B3;
    A1.x = fmaf(c1, u1.x, fmaf(c2, u2.x, fmaf(c3, u3.x, x[0].x)));
    A1.y = fmaf(c1, u1.y, fmaf(c2, u2.y, fmaf(c3, u3.y, x[0].y)));
    A2.x = fmaf(c2, u1.x, fmaf(c3, u2.x, fmaf(c1, u3.x, x[0].x)));
    A2.y = fmaf(c2, u1.y, fmaf(c3, u2.y, fmaf(c1, u3.y, x[0].y)));
    A3.x = fmaf(c3, u1.x, fmaf(c1, u2.x, fmaf(c2, u3.x, x[0].x)));
    A3.y = fmaf(c3, u1.y, fmaf(c1, u2.y, fmaf(c2, u3.y, x[0].y)));
    B1.x = fmaf(s1, v1.x, fmaf(s2, v2.x,  s3 * v3.x));
    B1.y = fmaf(s1, v1.y, fmaf(s2, v2.y,  s3 * v3.y));
    B2.x = fmaf(s2, v1.x, fmaf(-s3, v2.x, -s1 * v3.x));
    B2.y = fmaf(s2, v1.y, fmaf(-s3, v2.y, -s1 * v3.y));
    B3.x = fmaf(s3, v1.x, fmaf(-s1, v2.x,  s2 * v3.x));
    B3.y = fmaf(s3, v1.y, fmaf(-s1, v2.y,  s2 * v3.y));
    if (SGN > 0) {
        y[1] = make_float2(A1.x + B1.y, A1.y - B1.x);
        y[6] = make_float2(A1.x - B1.y, A1.y + B1.x);
        y[2] = make_float2(A2.x + B2.y, A2.y - B2.x);
        y[5] = make_float2(A2.x - B2.y, A2.y + B2.x);
        y[3] = make_float2(A3.x + B3.y, A3.y - B3.x);
        y[4] = make_float2(A3.x - B3.y, A3.y + B3.x);
    } else {
        y[1] = make_float2(A1.x - B1.y, A1.y + B1.x);
        y[6] = make_float2(A1.x + B1.y, A1.y - B1.x);
        y[2] = make_float2(A2.x - B2.y, A2.y + B2.x);
        y[5] = make_float2(A2.x + B2.y, A2.y - B2.x);
        y[3] = make_float2(A3.x - B3.y, A3.y + B3.x);
        y[4] = make_float2(A3.x + B3.y, A3.y - B3.x);
    }
}

// ---------- init kernels ----------
__global__ void k_init_misc(float2* __restrict__ tws, double* __restrict__ S) {
    int t = threadIdx.x;  // 1024 threads
    const double PI2 = 6.283185307179586476925287;
    if (t < 16)              { double s, c; sincos(-(PI2 * t) / 32.0, &s, &c); tws[TW_W32 + t] = make_float2((float)c, (float)s); }
    if (t >= 16 && t < 23)   { int j = t - 16; double s, c; sincos(-(PI2 * j) / 7.0,  &s, &c); tws[TW_W7 + j]  = make_float2((float)c, (float)s); }
    if (t >= 23 && t < 55)   { int j = t - 23; double s, c; sincos(-(PI2 * j) / 64.0, &s, &c); tws[TW_W64 + j] = make_float2((float)c, (float)s); }
    if (t >= 55 && t < 279)  { int j = t - 55;  int d7 = j >> 5, l = j & 31;
                               double s, c; sincos(-(PI2 * (d7 * l)) / 224.0, &s, &c);
                               tws[TW_T224 + j] = make_float2((float)c, (float)s); }
    if (t >= 279 && t < 727) { int j = t - 279; int d7 = j >> 6, l = j & 63;
                               double s, c; sincos(-(PI2 * (d7 * l)) / 448.0, &s, &c);
                               tws[TW_T448 + j] = make_float2((float)c, (float)s); }
    if (t >= 727 && t < 759) S[t - 727] = 0.0;
}

// float4-vectorized: fftshift halves (112 in w, 224 in h) are 4-divisible,
// so aligned quads map to aligned quads. One float4 (4 pixels) per thread.
__global__ void k_build_p(const float* __restrict__ z, const float* __restrict__ zf,
                          const float* __restrict__ miu,
                          float2* __restrict__ p, float2* __restrict__ r, float2* __restrict__ b,
                          double* __restrict__ S) {
    const int N4 = DHWn / 4;
    int e4 = blockIdx.x * blockDim.x + threadIdx.x;
    double acc = 0.0;
    if (e4 < N4) {
        float mu = fabsf(miu[0]);
        int e = 4 * e4;
        int d = e / HWn, rem = e - d * HWn;
        int h = rem / Wn, w = rem - h * Wn;            // w % 4 == 0
        int hs = h + Hn / 2; if (hs >= Hn) hs -= Hn;
        int ws = w + Wn / 2; if (ws >= Wn) ws -= Wn;   // ws % 4 == 0
        int src = d * HWn + hs * Wn + ws;
        float4 zr  = *(const float4*)&z[src];
        float4 zi  = *(const float4*)&z[DHWn + src];
        float4 fr  = *(const float4*)&zf[src];
        float4 fi  = *(const float4*)&zf[DHWn + src];
        float4 pa = make_float4(fmaf(mu, zr.x, fr.x), fmaf(mu, zi.x, fi.x),
                                fmaf(mu, zr.y, fr.y), fmaf(mu, zi.y, fi.y));
        float4 pb = make_float4(fmaf(mu, zr.z, fr.z), fmaf(mu, zi.z, fi.z),
                                fmaf(mu, zr.w, fr.w), fmaf(mu, zi.w, fi.w));
        ((float4*)p)[2 * e4] = pa; ((float4*)p)[2 * e4 + 1] = pb;
        ((float4*)r)[2 * e4] = pa; ((float4*)r)[2 * e4 + 1] = pb;
        ((float4*)b)[2 * e4] = make_float4(0.f, 0.f, 0.f, 0.f);
        ((float4*)b)[2 * e4 + 1] = make_float4(0.f, 0.f, 0.f, 0.f);
        acc = (double)pa.x * pa.x + (double)pa.y * pa.y
            + (double)pa.z * pa.z + (double)pa.w * pa.w
            + (double)pb.x * pb.x + (double)pb.y * pb.y
            + (double)pb.z * pb.z + (double)pb.w * pb.w;
    }
    acc = waveReduce(acc);
    if ((threadIdx.x & 63) == 0) atomicAdd(&S[0], acc);
}

__global__ void k_build_coil(const float* __restrict__ cr, const float* __restrict__ ci,
                             float2* __restrict__ coil) {
    const int N4 = Cn * HWn / 4;
    int e4 = blockIdx.x * blockDim.x + threadIdx.x;
    if (e4 >= N4) return;
    int e = 4 * e4;
    int c = e / HWn, rem = e - c * HWn;
    int h = rem / Wn, w = rem - h * Wn;
    int hs = h + Hn / 2; if (hs >= Hn) hs -= Hn;
    int ws = w + Wn / 2; if (ws >= Wn) ws -= Wn;
    int src = c * HWn + hs * Wn + ws;
    float4 vr = *(const float4*)&cr[src];
    float4 vi = *(const float4*)&ci[src];
    ((float4*)coil)[2 * e4]     = make_float4(vr.x, vi.x, vr.y, vi.y);
    ((float4*)coil)[2 * e4 + 1] = make_float4(vr.z, vi.z, vr.w, vi.w);
}

// permuted + shifted + scaled mask: maskP[L*448 + h], line L holds true
// frequency column w(L) = 7*brev5(L&31) + (L>>5)
__global__ void k_build_mask(const int* __restrict__ mask, float* __restrict__ maskP) {
    for (int e = blockIdx.x * blockDim.x + threadIdx.x; e < HWn; e += gridDim.x * blockDim.x) {
        int L = e / Hn, h = e - L * Hn;
        int w = 7 * brev5(L & 31) + (L >> 5);
        int hs = h + Hn / 2; if (hs >= Hn) hs -= Hn;
        int ws = w + Wn / 2; if (ws >= Wn) ws -= Wn;
        maskP[e] = (float)mask[hs * Wn + ws] * (1.0f / (float)HWn);
    }
}

// ---------- forward row FFT (224 = 7*32 lane-FFT), coil-mul, direct octet store ----------
// No LDS, no barriers. FUSED update_p: for it>=1, p = r + beta*p_old on the fly;
// global-coil-0 block stores p into Pnew (ping-pong, no races).
__global__ __launch_bounds__(256) void k_rowfft0(const float2* __restrict__ Pread,
                                                 const float2* __restrict__ Rv,
                                                 float2* __restrict__ Pnew,
                                                 const float2* __restrict__ coil,
                                                 float2* __restrict__ Y1T,
                                                 const float2* __restrict__ twg,
                                                 const double* __restrict__ S,
                                                 int chunkStart, int it) {
    int tid = threadIdx.x;
    int lane = tid & 63, wv = tid >> 6, hi = lane >> 5, l32 = lane & 31;
    int h0 = blockIdx.x * 8, d = blockIdx.y, cz = blockIdx.z;
    int row = h0 + 2 * wv + hi;
    const float2* w32g = twg + TW_W32;
    const float2* t224 = twg + TW_T224;

    size_t roff = (size_t)d * HWn + (size_t)row * Wn;
    const float2* prow = Pread + roff;
    const float2* crow = coil + (size_t)(chunkStart + cz) * HWn + (size_t)row * Wn;

    float2 pv[7];
    if (it == 0) {
#pragma unroll
        for (int b = 0; b < 7; ++b) pv[b] = prow[32 * b + l32];
    } else {
        float beta = (float)(S[it] / S[it - 1]);
        const float2* rrow = Rv + roff;
#pragma unroll
        for (int b = 0; b < 7; ++b) {
            float2 rv = rrow[32 * b + l32];
            float2 po = prow[32 * b + l32];
            pv[b] = make_float2(fmaf(beta, po.x, rv.x), fmaf(beta, po.y, rv.y));
        }
        if (chunkStart + cz == 0) {
            float2* pw = Pnew + roff;
#pragma unroll
            for (int b = 0; b < 7; ++b) pw[32 * b + l32] = pv[b];
        }
    }

    float2 xb[7];
#pragma unroll
    for (int b = 0; b < 7; ++b) xb[b] = cmul(pv[b], crow[32 * b + l32]);

    // DFT7 (Winograd)
    float2 y[7];
    dft7<1>(xb, y);
    // twiddle W224^{l32*d7} from table
#pragma unroll
    for (int d7 = 1; d7 < 7; ++d7) y[d7] = cmul(y[d7], t224[d7 * 32 + l32]);

    // FFT32 across each half-wave, DIF (sign-trick form: y' = (t + s*y)*weff)
#pragma unroll
    for (int s = 0; s < 5; ++s) {
        int dist = 16 >> s;
        float2 wst = w32g[(l32 & (dist - 1)) << s];
        bool h2 = (l32 & dist) != 0;
        float sg = h2 ? -1.f : 1.f;
        float2 weff = h2 ? wst : make_float2(1.f, 0.f);
#pragma unroll
        for (int d7 = 0; d7 < 7; ++d7) {
            float2 t = xgroup(y[d7], dist);
            float2 u = make_float2(fmaf(sg, y[d7].x, t.x), fmaf(sg, y[d7].y, t.y));
            y[d7] = cmul(u, weff);
        }
    }

    // direct store: line L = d7*32+l32 -> octet (L>>3), slot (L&7)
    float2* ybase = Y1T + ((size_t)cz * Dn + d) * (size_t)HWn;
    int oct0 = l32 >> 3, l8 = l32 & 7;
#pragma unroll
    for (int d7 = 0; d7 < 7; ++d7)
        ybase[(size_t)(4 * d7 + oct0) * OCT_F2 + (size_t)row * 8 + l8] = y[d7];
}

// ---------- column FFT448 + mask + IFFT448 ----------
// 256 threads = 4 waves; one block per HALF-octet (4 lines, 1 line/wave).
// dist-32: v_permlane32_swap. dist-1/2/8: DPP. Only dist 4/16 on LDS pipe.
#define CP 452
__global__ __launch_bounds__(256) void k_colfft(float2* __restrict__ Y1T,
                                                const float* __restrict__ maskP,
                                                const float2* __restrict__ twg) {
    __shared__ float2 ls[4][CP];
    int tid = threadIdx.x;               // 0..255
    int lane = tid & 63, wv = tid >> 6;  // 4 waves
    int oct = blockIdx.x;                // 28
    int byy = blockIdx.y;                // 24 = d + 12*half
    int d = (byy < 12) ? byy : byy - 12;
    int half = (byy < 12) ? 0 : 1;
    int cz = blockIdx.z;
    const float2* w64t = twg + TW_W64;
    const float2* t448 = twg + TW_T448;

    float2* base = Y1T + ((size_t)cz * Dn + d) * (size_t)HWn + (size_t)oct * OCT_F2
                 + 4 * half;             // slots 4*half .. 4*half+3

    // stage in: 448 h x 4 slots = 1792 f2 = 896 f4 (two f4 per h)
#pragma unroll
    for (int m = 0; m < 4; ++m) {
        int j4 = tid + m * 256;
        if (j4 < 896) {
            int h = j4 >> 1, q = j4 & 1;     // f4 covers local slots 2q, 2q+1 at col h
            float4 v = *(const float4*)&base[(size_t)h * 8 + 2 * q];
            ls[2 * q][h]     = make_float2(v.x, v.y);
            ls[2 * q + 1][h] = make_float2(v.z, v.w);
        }
    }
    __syncthreads();

    int L = oct * 8 + 4 * half + wv;     // this wave's line

    float2 xb[7];
#pragma unroll
    for (int b = 0; b < 7; ++b) xb[b] = ls[wv][64 * b + lane];

    // twiddles W448^{lane*d7} (reused conjugated in the inverse pass)
    float2 tp[7];
#pragma unroll
    for (int d7 = 1; d7 < 7; ++d7) tp[d7] = t448[d7 * 64 + lane];

    // forward DFT7 (Winograd) + W448 twiddle
    float2 y[7];
    dft7<1>(xb, y);
#pragma unroll
    for (int d7 = 1; d7 < 7; ++d7) y[d7] = cmul(y[d7], tp[d7]);

    // ---- forward FFT64, stage dist=32 ----
    {
        float2 wst = w64t[lane & 31];
#pragma unroll
        for (int p = 0; p < 3; ++p) {
            float2 u = y[2 * p], v = y[2 * p + 1];
            swap32f(u.x, v.x); swap32f(u.y, v.y);    // u={lo_u,lo_v}, v={hi_u,hi_v}
            y[2 * p]     = cadd(u, v);               // S (no twiddle)
            y[2 * p + 1] = cmul(csub(u, v), wst);    // D * w
        }
        // y[6] classic
        bool hb = lane >= 32;
        float sg = hb ? -1.f : 1.f;
        float2 weff = hb ? wst : make_float2(1.f, 0.f);
        float2 t = shflx2(y[6], 32);
        float2 u6 = make_float2(fmaf(sg, y[6].x, t.x), fmaf(sg, y[6].y, t.y));
        y[6] = cmul(u6, weff);
    }
    // stages dist=16..1 (within 32-halves; identical for packed regs)
#pragma unroll
    for (int s = 1; s < 6; ++s) {
        int dist = 32 >> s;
        float2 wst = w64t[(lane & (dist - 1)) << s];
        bool hb = (lane & dist) != 0;
        float sg = hb ? -1.f : 1.f;
        float2 weff = hb ? wst : make_float2(1.f, 0.f);
#pragma unroll
        for (int d7 = 0; d7 < 7; ++d7) {
            float2 t = xgroup(y[d7], dist);
            float2 u = make_float2(fmaf(sg, y[d7].x, t.x), fmaf(sg, y[d7].y, t.y));
            y[d7] = cmul(u, weff);
        }
    }

    // mask. Packed regs: subtree bit 0 for S-regs (2p), 1 for D-regs (2p+1);
    // d7 = 2p for lanes<32 (u), 2p+1 for lanes>=32 (v).
    {
        int rb0 = brev5(lane & 31) << 1;
        const float* mbase = maskP + (size_t)L * Hn;
        bool lo = lane < 32;
#pragma unroll
        for (int p = 0; p < 3; ++p) {
            int dsel = lo ? (2 * p) : (2 * p + 1);
            float mS = mbase[7 * rb0 + dsel];
            float mD = mbase[7 * (rb0 + 1) + dsel];
            y[2 * p].x *= mS;     y[2 * p].y *= mS;
            y[2 * p + 1].x *= mD; y[2 * p + 1].y *= mD;
        }
        int rb6 = rb0 | (lane >> 5);
        float m6 = mbase[7 * rb6 + 6];
        y[6].x *= m6; y[6].y *= m6;
    }

    // inverse FFT64, DIT stages dist=1..16 (within halves; packed-safe)
#pragma unroll
    for (int s = 0; s < 5; ++s) {
        int dist = 1 << s;
        float2 wst = w64t[(lane & (dist - 1)) << (5 - s)];
        wst.y = -wst.y;
        bool hb = (lane & dist) != 0;
        float2 c = hb ? make_float2(-wst.x, -wst.y) : wst;
#pragma unroll
        for (int d7 = 0; d7 < 7; ++d7) {
            float2 t = xgroup(y[d7], dist);
            float2 B = hb ? y[d7] : t;
            float2 A = hb ? t : y[d7];
            y[d7] = cfma(c, B, A);
        }
    }
    // ---- final inverse stage dist=32 ----
    {
        float2 wst = w64t[lane & 31];
        float2 cw  = make_float2(wst.x, -wst.y);    // conj
        float2 ncw = make_float2(-cw.x, -cw.y);
#pragma unroll
        for (int p = 0; p < 3; ++p) {
            float2 S = y[2 * p], D = y[2 * p + 1];  // S={u_e,v_e}, D={u_o,v_o}
            float2 T1 = cfma(cw,  D, S);            // even + cw*odd  -> out.lo
            float2 T2 = cfma(ncw, D, S);            // even - cw*odd  -> out.hi
            swap32f(T1.x, T2.x); swap32f(T1.y, T2.y);  // -> (u_out, v_out)
            y[2 * p] = T1; y[2 * p + 1] = T2;
        }
        // y[6] classic
        bool hb = lane >= 32;
        float2 c = hb ? ncw : cw;
        float2 t = shflx2(y[6], 32);
        float2 B = hb ? y[6] : t;
        float2 A = hb ? t : y[6];
        y[6] = cfma(c, B, A);
    }

    // conj W448 twiddle + inverse DFT7 (Winograd) + LDS writeback
#pragma unroll
    for (int d7 = 1; d7 < 7; ++d7) {
        float2 c = make_float2(tp[d7].x, -tp[d7].y);
        y[d7] = cmul(y[d7], c);
    }
    dft7<-1>(y, xb);
#pragma unroll
    for (int b = 0; b < 7; ++b) ls[wv][64 * b + lane] = xb[b];
    __syncthreads();

    // stage out: mirror of stage in
#pragma unroll
    for (int m = 0; m < 4; ++m) {
        int j4 = tid + m * 256;
        if (j4 < 896) {
            int h = j4 >> 1, q = j4 & 1;
            float2 a = ls[2 * q][h];
            float2 b = ls[2 * q + 1][h];
            *(float4*)&base[(size_t)h * 8 + 2 * q] = make_float4(a.x, a.y, b.x, b.y);
        }
    }
}

// ---------- fused inverse row FFT + conj-coil + coil-sum + q/dot epilogue ----------
__global__ __launch_bounds__(256) void k_irow_combine(const float2* __restrict__ Y1T,
                                                      const float2* __restrict__ coil,
                                                      const float2* __restrict__ P,
                                                      float2* __restrict__ Qp,
                                                      const float* __restrict__ miu,
                                                      double* __restrict__ S,
                                                      const float2* __restrict__ twg,
                                                      int ccz, int chunkStart,
                                                      int first, int last, int it) {
    __shared__ double sred[8];
    int tid = threadIdx.x;
    int lane = tid & 63, wv = tid >> 6, hi = lane >> 5, l32 = lane & 31;
    int h0 = blockIdx.x * 8, d = blockIdx.y;
    int zid = blockIdx.z;
    int zbase = zid * ccz;
    float2* Q = Qp + (size_t)zid * DHWn;
    int row = h0 + 2 * wv + hi;
    const float2* w32g = twg + TW_W32;
    const float2* t224 = twg + TW_T224;

    float2 tp[7];
#pragma unroll
    for (int d7 = 1; d7 < 7; ++d7) {
        float2 v = t224[d7 * 32 + l32];
        tp[d7] = make_float2(v.x, -v.y);   // conj (inverse twiddle)
    }

    float2 acc[7];
#pragma unroll
    for (int b = 0; b < 7; ++b) acc[b] = make_float2(0.f, 0.f);

    int oct0 = l32 >> 3, l8 = l32 & 7;
    for (int cz = 0; cz < ccz; ++cz) {
        const float2* ybase = Y1T + ((size_t)(zbase + cz) * Dn + d) * (size_t)HWn;
        const float2* crow = coil + (size_t)(chunkStart + zbase + cz) * HWn + (size_t)row * Wn;

        // DIT-ready register loads: y[d7] = line (d7*32+l32) at this row
        float2 y[7];
#pragma unroll
        for (int d7 = 0; d7 < 7; ++d7)
            y[d7] = ybase[(size_t)(4 * d7 + oct0) * OCT_F2 + (size_t)row * 8 + l8];
        float2 cpre[7];
#pragma unroll
        for (int b = 0; b < 7; ++b) cpre[b] = crow[32 * b + l32];

        // inverse FFT32 across half-wave, DIT (sign-trick): y' = A + c*B
#pragma unroll
        for (int s = 0; s < 5; ++s) {
            int dist = 1 << s;
            float2 wst = w32g[(l32 & (dist - 1)) << (4 - s)];
            wst.y = -wst.y;
            bool h2 = (l32 & dist) != 0;
            float2 c = h2 ? make_float2(-wst.x, -wst.y) : wst;
#pragma unroll
            for (int d7 = 0; d7 < 7; ++d7) {
                float2 t = xgroup(y[d7], dist);
                float2 B = h2 ? y[d7] : t;
                float2 A = h2 ? t : y[d7];
                y[d7] = cfma(c, B, A);
            }
        }
        // conj twiddle W224^{-l32*d7}
#pragma unroll
        for (int d7 = 1; d7 < 7; ++d7) y[d7] = cmul(y[d7], tp[d7]);
        // inverse DFT7 (Winograd) + conj-coil accumulate
        float2 s7[7];
        dft7<-1>(y, s7);
#pragma unroll
        for (int b = 0; b < 7; ++b) {
            float2 s = s7[b];
            float2 c = cpre[b];
            acc[b].x += fmaf(s.x, c.x, s.y * c.y);
            acc[b].y += fmaf(s.y, c.x, -s.x * c.y);
        }
    }

    // epilogue: partial q; only zid==0 folds in mu*p (exactly once in the sum).
    float mu = fabsf(miu[0]);
    const float2* prow = P + (size_t)d * HWn + (size_t)row * Wn;
    float2* qrow = Q + (size_t)d * HWn + (size_t)row * Wn;
    double ar = 0.0, ai = 0.0;
#pragma unroll
    for (int b = 0; b < 7; ++b) {
        float2 pv = prow[32 * b + l32];
        float2 s0;
        if (first) {
            if (zid == 0) s0 = make_float2(fmaf(mu, pv.x, acc[b].x), fmaf(mu, pv.y, acc[b].y));
            else          s0 = acc[b];
        } else {
            float2 qv = qrow[32 * b + l32];
            s0 = cadd(qv, acc[b]);
        }
        qrow[32 * b + l32] = s0;
        if (last) {
            ar += (double)(s0.x * pv.x + s0.y * pv.y);
            ai += (double)(s0.y * pv.x - s0.x * pv.y);
        }
    }
    if (last) {
        ar = waveReduce(ar);
        ai = waveReduce(ai);
        if (lane == 0) { sred[wv] = ar; sred[4 + wv] = ai; }
        __syncthreads();
        if (tid == 0) {
            atomicAdd(&S[8 + it],  sred[0] + sred[1] + sred[2] + sred[3]);
            atomicAdd(&S[16 + it], sred[4] + sred[5] + sred[6] + sred[7]);
        }
    }
}

// ---------- CG scalar update (float4 = 2 complex per lane) ----------
__global__ void k_update_br(const double* __restrict__ Sin, double* __restrict__ S, int it,
                            const float4* __restrict__ p, const float4* __restrict__ q,
                            int nz,
                            float4* __restrict__ b, float4* __restrict__ r) {
    double rr = Sin[it], qr = Sin[8 + it], qi = Sin[16 + it];
    double den = qr * qr + qi * qi;
    float arf = (float)(rr * qr / den);
    float aif = (float)(-rr * qi / den);
    double acc = 0.0;
    const int N2 = DHWn / 2;
    for (int e = blockIdx.x * blockDim.x + threadIdx.x; e < N2; e += gridDim.x * blockDim.x) {
        float4 pv = p[e], bv = b[e], rv = r[e];
        float4 qv = q[e];
        for (int z = 1; z < nz; ++z) {
            float4 t = q[(size_t)z * N2 + e];
            qv.x += t.x; qv.y += t.y; qv.z += t.z; qv.w += t.w;
        }
        bv.x += arf * pv.x - aif * pv.y;  bv.y += arf * pv.y + aif * pv.x;
        bv.z += arf * pv.z - aif * pv.w;  bv.w += arf * pv.w + aif * pv.z;
        b[e] = bv;
        rv.x -= arf * qv.x - aif * qv.y;  rv.y -= arf * qv.y + aif * qv.x;
        rv.z -= arf * qv.z - aif * qv.w;  rv.w -= arf * qv.w + aif * qv.z;
        r[e] = rv;
        acc += (double)rv.x * rv.x + (double)rv.y * rv.y
             + (double)rv.z * rv.z + (double)rv.w * rv.w;
    }
    acc = waveReduce(acc);
    if ((threadIdx.x & 63) == 0) atomicAdd(&S[it + 1], acc);
}

// float4-vectorized output (shift-aligned quads, same argument as k_build_p)
__global__ void k_output(const float2* __restrict__ b, float* __restrict__ out) {
    const int N4 = DHWn / 4;
    int e4 = blockIdx.x * blockDim.x + threadIdx.x;
    if (e4 >= N4) return;
    int e = 4 * e4;
    int d = e / HWn, rem = e - d * HWn;
    int h = rem / Wn, w = rem - h * Wn;
    int hs = h + Hn / 2; if (hs >= Hn) hs -= Hn;
    int ws = w + Wn / 2; if (ws >= Wn) ws -= Wn;
    int src = d * HWn + hs * Wn + ws;                  // src % 4 == 0
    float4 a  = ((const float4*)b)[src / 2];
    float4 bb = ((const float4*)b)[src / 2 + 1];
    *(float4*)&out[e]        = make_float4(a.x, a.z, bb.x, bb.z);
    *(float4*)&out[DHWn + e] = make_float4(a.y, a.w, bb.y, bb.w);
}

extern "C" void kernel_launch(void* const* d_in, const int* in_sizes, int n_in,
                              void* d_out, int out_size, void* d_ws, size_t ws_size,
                              hipStream_t stream) {
    const float* z      = (const float*)d_in[0];
    const float* zf     = (const float*)d_in[1];
    const float* coil_r = (const float*)d_in[2];
    const float* coil_i = (const float*)d_in[3];
    const int*   maskp  = (const int*)d_in[4];
    const float* miu    = (const float*)d_in[5];
    float* out = (float*)d_out;

    char* w = (char*)d_ws;
    size_t off = 0;
    auto carve = [&](size_t bytes) -> void* {
        void* ptr = w + off;
        off += (bytes + 511) & ~(size_t)511;
        return ptr;
    };
    float2* P0    = (float2*)carve((size_t)DHWn * 8);
    float2* P1    = (float2*)carve((size_t)DHWn * 8);
    float2* R     = (float2*)carve((size_t)DHWn * 8);
    float2* Bv    = (float2*)carve((size_t)DHWn * 8);
    float2* COIL  = (float2*)carve((size_t)Cn * HWn * 8);
    float*  MASKP = (float*)carve((size_t)HWn * 4);
    float2* TWS   = (float2*)carve(TW_NT * 8);
    double* S     = (double*)carve(64 * 8);

    size_t imgSet = (size_t)DHWn * 8;   // one coil-slot (12 slices), 9.63 MB
    // (coils staged per chunk, z-splits of the combine); NZ divides cc.
    int cc = 1, NZ = 1;
    {
        const int cand[6][2] = {{10,2},{10,1},{5,1},{2,1},{1,1},{1,1}};
        for (int i = 0; i < 6; ++i) {
            size_t need = off + (size_t)(cand[i][0] + cand[i][1]) * imgSet;
            if (need <= ws_size) { cc = cand[i][0]; NZ = cand[i][1]; break; }
        }
    }
    float2* Qp  = (float2*)carve((size_t)NZ * imgSet);   // NZ partial-q buffers
    float2* Y1T = (float2*)carve((size_t)cc * imgSet);   // staged slices [c][d][oct][h][l8]
    int nch = Cn / cc;
    int ccz = cc / NZ;

    k_init_misc<<<1, 1024, 0, stream>>>(TWS, S);
    k_build_p<<<(DHWn / 4 + 255) / 256, 256, 0, stream>>>(z, zf, miu, P0, R, Bv, S);
    k_build_coil<<<(Cn * HWn / 4 + 255) / 256, 256, 0, stream>>>(coil_r, coil_i, COIL);
    k_build_mask<<<512, 256, 0, stream>>>(maskp, MASKP);

    for (int it = 0; it < 5; ++it) {
        float2* Pcur = (it & 1) ? P1 : P0;     // p for this iteration
        float2* Pold = (it & 1) ? P0 : P1;     // previous p (read source for it>=1)
        const float2* Pread = (it == 0) ? Pcur : Pold;
        for (int ch = 0; ch < nch; ++ch) {
            int cs = ch * cc;
            dim3 gf(Hn / 8, Dn, cc);    // 56 x 12 x cc
            dim3 gc(28, 24, cc);        // octet x (d + 12*half) x cc
            dim3 gi(Hn / 8, Dn, NZ);    // 56 x 12 x NZ, each z does cc/NZ coils
            k_rowfft0<<<gf, 256, 0, stream>>>(Pread, R, Pcur, COIL, Y1T, TWS, S, cs, it);
            k_colfft<<<gc, 256, 0, stream>>>(Y1T, MASKP, TWS);
            k_irow_combine<<<gi, 256, 0, stream>>>(Y1T, COIL, Pcur, Qp, miu, S, TWS,
                                                   ccz, cs, ch == 0 ? 1 : 0,
                                                   ch == nch - 1 ? 1 : 0, it);
        }
        k_update_br<<<1024, 256, 0, stream>>>(S, S, it, (const float4*)Pcur, (const float4*)Qp,
                                              NZ, (float4*)Bv, (float4*)R);
    }
    k_output<<<(DHWn / 4 + 255) / 256, 256, 0, stream>>>(Bv, out);
}

// Round 17
// 815.092 us; speedup vs baseline: 1.3774x; 1.2469x over previous
//
#include <hip/hip_runtime.h>
#include <math.h>

// Problem constants (fixed shapes from setup_inputs)
#define Dn   12
#define Hn   448
#define Wn   224
#define HWn  (Hn*Wn)        // 100352
#define DHWn (Dn*HWn)       // 1204224
#define Cn   10

// Y1T layout is OCTET-BLOCKED per slice (c,d): element (L, h) stored at
//   (L>>3)*3584 + h*8 + (L&7)        (3584 = 448*8; octet = 28 KB contiguous)
// where L is the bit-rev-permuted line index (identity L = d7*32+l32).
#define OCT_F2 3584

// Twiddle table (float2 in global):
#define TW_W32   0     // 16:  W32^j
#define TW_W7    16    // 7:   W7^j (unused by Winograd path, kept for layout)
#define TW_W64   23    // 32:  W64^j
#define TW_T224  55    // 224: W224^{d7*l32}  [d7*32+l32]
#define TW_T448  279   // 448: W448^{d7*lane} [d7*64+lane]
#define TW_NT    727

// Scalar accumulator layout (doubles), 8-way slot-spread to avoid same-address
// atomic serialization (~34 cy/atomic measured):
//   S[8*it + j]        : rr slots, it = 0..5
//   S[64 + 8*it + j]   : qr slots, it = 0..4
//   S[128 + 8*it + j]  : qi slots, it = 0..4
#define S_NDBL 256

// ---------- complex helpers ----------
__device__ __forceinline__ float2 cmul(float2 a, float2 b) {
    return make_float2(fmaf(a.x, b.x, -a.y * b.y), fmaf(a.x, b.y, a.y * b.x));
}
__device__ __forceinline__ float2 cfma(float2 a, float2 b, float2 acc) {
    acc.x = fmaf(a.x, b.x, fmaf(-a.y, b.y, acc.x));
    acc.y = fmaf(a.x, b.y, fmaf(a.y, b.x, acc.y));
    return acc;
}
__device__ __forceinline__ float2 cadd(float2 a, float2 b) { return make_float2(a.x + b.x, a.y + b.y); }
__device__ __forceinline__ float2 csub(float2 a, float2 b) { return make_float2(a.x - b.x, a.y - b.y); }
__host__ __device__ constexpr int brev5(int i) {
    return ((i & 1) << 4) | ((i & 2) << 2) | (i & 4) | ((i & 8) >> 2) | ((i & 16) >> 4);
}

__device__ __forceinline__ float2 shflx2(float2 v, int m) {
    return make_float2(__shfl_xor(v.x, m, 64), __shfl_xor(v.y, m, 64));
}

// DPP lane exchanges (VALU pipe, not LDS):
//   xor-1 = quad_perm [1,0,3,2] = 0xB1; xor-2 = quad_perm [2,3,0,1] = 0x4E;
//   xor-8 = row_ror:8 = 0x128  ((i+8) mod 16 == i^8 within each 16-lane row).
template<int CTRL>
__device__ __forceinline__ float dppmov(float x) {
    return __int_as_float(__builtin_amdgcn_update_dpp(
        0, __float_as_int(x), CTRL, 0xF, 0xF, true));
}
__device__ __forceinline__ float2 xgroup(float2 v, int dist) {
    if (dist == 1) return make_float2(dppmov<0xB1>(v.x),  dppmov<0xB1>(v.y));
    if (dist == 2) return make_float2(dppmov<0x4E>(v.x),  dppmov<0x4E>(v.y));
    if (dist == 8) return make_float2(dppmov<0x128>(v.x), dppmov<0x128>(v.y));
    return shflx2(v, dist);
}

// v_permlane32_swap_b32 (VALU pipe): a'={a.lo, b.lo}, b'={a.hi, b.hi}.
typedef unsigned int uv2 __attribute__((ext_vector_type(2)));
__device__ __forceinline__ void swap32f(float &a, float &b) {
    uv2 r = __builtin_amdgcn_permlane32_swap(__float_as_uint(a), __float_as_uint(b), false, false);
    a = __uint_as_float(r.x);
    b = __uint_as_float(r.y);
}

__device__ __forceinline__ double waveReduce(double v) {
#pragma unroll
    for (int o = 32; o > 0; o >>= 1) v += __shfl_down(v, o, 64);
    return v;
}
__device__ __forceinline__ double sum8(const double* __restrict__ p) {
    return ((p[0] + p[1]) + (p[2] + p[3])) + ((p[4] + p[5]) + (p[6] + p[7]));
}

// ---------- Winograd-style DFT-7 (66 VALU ops vs 168 naive) ----------
template<int SGN>
__device__ __forceinline__ void dft7(const float2* __restrict__ x, float2* __restrict__ y) {
    const float c1 =  0.62348980185873359f;   // cos(2pi/7)
    const float c2 = -0.22252093395631445f;   // cos(4pi/7)
    const float c3 = -0.90096886790241915f;   // cos(6pi/7)
    const float s1 =  0.78183148246802980f;   // sin(2pi/7)
    const float s2 =  0.97492791218182362f;   // sin(4pi/7)
    const float s3 =  0.43388373911755823f;   // sin(6pi/7)
    float2 u1 = cadd(x[1], x[6]), v1 = csub(x[1], x[6]);
    float2 u2 = cadd(x[2], x[5]), v2 = csub(x[2], x[5]);
    float2 u3 = cadd(x[3], x[4]), v3 = csub(x[3], x[4]);
    y[0] = make_float2(x[0].x + u1.x + u2.x + u3.x,
                       x[0].y + u1.y + u2.y + u3.y);
    float2 A1, A2, A3, B1, B2, B3;
    A1.x = fmaf(c1, u1.x, fmaf(c2, u2.x, fmaf(c3, u3.x, x[0].x)));
    A1.y = fmaf(c1, u1.y, fmaf(c2, u2.y, fmaf(c3, u3.y, x[0].y)));
    A2.x = fmaf(c2, u1.x, fmaf(c3, u2.x, fmaf(c1, u3.x, x[0].x)));
    A2.y = fmaf(c2, u1.y, fmaf(c3, u2.y, fmaf(c1, u3.y, x[0].y)));
    A3.x = fmaf(c3, u1.x, fmaf(c1, u2.x, fmaf(c2, u3.x, x[0].x)));
    A3.y = fmaf(c3, u1.y, fmaf(c1, u2.y, fmaf(c2, u3.y, x[0].y)));
    B1.x = fmaf(s1, v1.x, fmaf(s2, v2.x,  s3 * v3.x));
    B1.y = fmaf(s1, v1.y, fmaf(s2, v2.y,  s3 * v3.y));
    B2.x = fmaf(s2, v1.x, fmaf(-s3, v2.x, -s1 * v3.x));
    B2.y = fmaf(s2, v1.y, fmaf(-s3, v2.y, -s1 * v3.y));
    B3.x = fmaf(s3, v1.x, fmaf(-s1, v2.x,  s2 * v3.x));
    B3.y = fmaf(s3, v1.y, fmaf(-s1, v2.y,  s2 * v3.y));
    if (SGN > 0) {
        y[1] = make_float2(A1.x + B1.y, A1.y - B1.x);
        y[6] = make_float2(A1.x - B1.y, A1.y + B1.x);
        y[2] = make_float2(A2.x + B2.y, A2.y - B2.x);
        y[5] = make_float2(A2.x - B2.y, A2.y + B2.x);
        y[3] = make_float2(A3.x + B3.y, A3.y - B3.x);
        y[4] = make_float2(A3.x - B3.y, A3.y + B3.x);
    } else {
        y[1] = make_float2(A1.x - B1.y, A1.y + B1.x);
        y[6] = make_float2(A1.x + B1.y, A1.y - B1.x);
        y[2] = make_float2(A2.x - B2.y, A2.y + B2.x);
        y[5] = make_float2(A2.x + B2.y, A2.y - B2.x);
        y[3] = make_float2(A3.x - B3.y, A3.y + B3.x);
        y[4] = make_float2(A3.x + B3.y, A3.y - B3.x);
    }
}

// ---------- init kernels ----------
__global__ void k_init_misc(float2* __restrict__ tws, double* __restrict__ S) {
    int t = threadIdx.x;  // 1024 threads
    const double PI2 = 6.283185307179586476925287;
    if (t < 16)              { double s, c; sincos(-(PI2 * t) / 32.0, &s, &c); tws[TW_W32 + t] = make_float2((float)c, (float)s); }
    if (t >= 16 && t < 23)   { int j = t - 16; double s, c; sincos(-(PI2 * j) / 7.0,  &s, &c); tws[TW_W7 + j]  = make_float2((float)c, (float)s); }
    if (t >= 23 && t < 55)   { int j = t - 23; double s, c; sincos(-(PI2 * j) / 64.0, &s, &c); tws[TW_W64 + j] = make_float2((float)c, (float)s); }
    if (t >= 55 && t < 279)  { int j = t - 55;  int d7 = j >> 5, l = j & 31;
                               double s, c; sincos(-(PI2 * (d7 * l)) / 224.0, &s, &c);
                               tws[TW_T224 + j] = make_float2((float)c, (float)s); }
    if (t >= 279 && t < 727) { int j = t - 279; int d7 = j >> 6, l = j & 63;
                               double s, c; sincos(-(PI2 * (d7 * l)) / 448.0, &s, &c);
                               tws[TW_T448 + j] = make_float2((float)c, (float)s); }
    if (t >= 727 && t < 727 + S_NDBL) S[t - 727] = 0.0;
}

// float4-vectorized; per-block LDS reduction -> ONE slot-spread atomic/block.
__global__ void k_build_p(const float* __restrict__ z, const float* __restrict__ zf,
                          const float* __restrict__ miu,
                          float2* __restrict__ p, float2* __restrict__ r, float2* __restrict__ b,
                          double* __restrict__ S) {
    __shared__ double sred[4];
    const int N4 = DHWn / 4;
    int e4 = blockIdx.x * blockDim.x + threadIdx.x;
    double acc = 0.0;
    if (e4 < N4) {
        float mu = fabsf(miu[0]);
        int e = 4 * e4;
        int d = e / HWn, rem = e - d * HWn;
        int h = rem / Wn, w = rem - h * Wn;            // w % 4 == 0
        int hs = h + Hn / 2; if (hs >= Hn) hs -= Hn;
        int ws = w + Wn / 2; if (ws >= Wn) ws -= Wn;   // ws % 4 == 0
        int src = d * HWn + hs * Wn + ws;
        float4 zr  = *(const float4*)&z[src];
        float4 zi  = *(const float4*)&z[DHWn + src];
        float4 fr  = *(const float4*)&zf[src];
        float4 fi  = *(const float4*)&zf[DHWn + src];
        float4 pa = make_float4(fmaf(mu, zr.x, fr.x), fmaf(mu, zi.x, fi.x),
                                fmaf(mu, zr.y, fr.y), fmaf(mu, zi.y, fi.y));
        float4 pb = make_float4(fmaf(mu, zr.z, fr.z), fmaf(mu, zi.z, fi.z),
                                fmaf(mu, zr.w, fr.w), fmaf(mu, zi.w, fi.w));
        ((float4*)p)[2 * e4] = pa; ((float4*)p)[2 * e4 + 1] = pb;
        ((float4*)r)[2 * e4] = pa; ((float4*)r)[2 * e4 + 1] = pb;
        ((float4*)b)[2 * e4] = make_float4(0.f, 0.f, 0.f, 0.f);
        ((float4*)b)[2 * e4 + 1] = make_float4(0.f, 0.f, 0.f, 0.f);
        acc = (double)pa.x * pa.x + (double)pa.y * pa.y
            + (double)pa.z * pa.z + (double)pa.w * pa.w
            + (double)pb.x * pb.x + (double)pb.y * pb.y
            + (double)pb.z * pb.z + (double)pb.w * pb.w;
    }
    acc = waveReduce(acc);
    if ((threadIdx.x & 63) == 0) sred[threadIdx.x >> 6] = acc;
    __syncthreads();
    if (threadIdx.x == 0)
        atomicAdd(&S[blockIdx.x & 7], (sred[0] + sred[1]) + (sred[2] + sred[3]));
}

__global__ void k_build_coil(const float* __restrict__ cr, const float* __restrict__ ci,
                             float2* __restrict__ coil) {
    const int N4 = Cn * HWn / 4;
    int e4 = blockIdx.x * blockDim.x + threadIdx.x;
    if (e4 >= N4) return;
    int e = 4 * e4;
    int c = e / HWn, rem = e - c * HWn;
    int h = rem / Wn, w = rem - h * Wn;
    int hs = h + Hn / 2; if (hs >= Hn) hs -= Hn;
    int ws = w + Wn / 2; if (ws >= Wn) ws -= Wn;
    int src = c * HWn + hs * Wn + ws;
    float4 vr = *(const float4*)&cr[src];
    float4 vi = *(const float4*)&ci[src];
    ((float4*)coil)[2 * e4]     = make_float4(vr.x, vi.x, vr.y, vi.y);
    ((float4*)coil)[2 * e4 + 1] = make_float4(vr.z, vi.z, vr.w, vi.w);
}

// permuted + shifted + scaled mask: maskP[L*448 + h]
__global__ void k_build_mask(const int* __restrict__ mask, float* __restrict__ maskP) {
    for (int e = blockIdx.x * blockDim.x + threadIdx.x; e < HWn; e += gridDim.x * blockDim.x) {
        int L = e / Hn, h = e - L * Hn;
        int w = 7 * brev5(L & 31) + (L >> 5);
        int hs = h + Hn / 2; if (hs >= Hn) hs -= Hn;
        int ws = w + Wn / 2; if (ws >= Wn) ws -= Wn;
        maskP[e] = (float)mask[hs * Wn + ws] * (1.0f / (float)HWn);
    }
}

// ---------- forward row FFT (224 = 7*32 lane-FFT), coil-mul, direct octet store ----------
// FUSED update_p: for it>=1, p = r + beta*p_old (beta from slot sums).
__global__ __launch_bounds__(256) void k_rowfft0(const float2* __restrict__ Pread,
                                                 const float2* __restrict__ Rv,
                                                 float2* __restrict__ Pnew,
                                                 const float2* __restrict__ coil,
                                                 float2* __restrict__ Y1T,
                                                 const float2* __restrict__ twg,
                                                 const double* __restrict__ S,
                                                 int chunkStart, int it) {
    int tid = threadIdx.x;
    int lane = tid & 63, wv = tid >> 6, hi = lane >> 5, l32 = lane & 31;
    int h0 = blockIdx.x * 8, d = blockIdx.y, cz = blockIdx.z;
    int row = h0 + 2 * wv + hi;
    const float2* w32g = twg + TW_W32;
    const float2* t224 = twg + TW_T224;

    size_t roff = (size_t)d * HWn + (size_t)row * Wn;
    const float2* prow = Pread + roff;
    const float2* crow = coil + (size_t)(chunkStart + cz) * HWn + (size_t)row * Wn;

    float2 pv[7];
    if (it == 0) {
#pragma unroll
        for (int b = 0; b < 7; ++b) pv[b] = prow[32 * b + l32];
    } else {
        float beta = (float)(sum8(S + 8 * it) / sum8(S + 8 * (it - 1)));
        const float2* rrow = Rv + roff;
#pragma unroll
        for (int b = 0; b < 7; ++b) {
            float2 rv = rrow[32 * b + l32];
            float2 po = prow[32 * b + l32];
            pv[b] = make_float2(fmaf(beta, po.x, rv.x), fmaf(beta, po.y, rv.y));
        }
        if (chunkStart + cz == 0) {
            float2* pw = Pnew + roff;
#pragma unroll
            for (int b = 0; b < 7; ++b) pw[32 * b + l32] = pv[b];
        }
    }

    float2 xb[7];
#pragma unroll
    for (int b = 0; b < 7; ++b) xb[b] = cmul(pv[b], crow[32 * b + l32]);

    // DFT7 (Winograd)
    float2 y[7];
    dft7<1>(xb, y);
#pragma unroll
    for (int d7 = 1; d7 < 7; ++d7) y[d7] = cmul(y[d7], t224[d7 * 32 + l32]);

    // FFT32 across each half-wave, DIF (sign-trick form)
#pragma unroll
    for (int s = 0; s < 5; ++s) {
        int dist = 16 >> s;
        float2 wst = w32g[(l32 & (dist - 1)) << s];
        bool h2 = (l32 & dist) != 0;
        float sg = h2 ? -1.f : 1.f;
        float2 weff = h2 ? wst : make_float2(1.f, 0.f);
#pragma unroll
        for (int d7 = 0; d7 < 7; ++d7) {
            float2 t = xgroup(y[d7], dist);
            float2 u = make_float2(fmaf(sg, y[d7].x, t.x), fmaf(sg, y[d7].y, t.y));
            y[d7] = cmul(u, weff);
        }
    }

    // direct store: line L = d7*32+l32 -> octet (L>>3), slot (L&7)
    float2* ybase = Y1T + ((size_t)cz * Dn + d) * (size_t)HWn;
    int oct0 = l32 >> 3, l8 = l32 & 7;
#pragma unroll
    for (int d7 = 0; d7 < 7; ++d7)
        ybase[(size_t)(4 * d7 + oct0) * OCT_F2 + (size_t)row * 8 + l8] = y[d7];
}

// ---------- column FFT448 + mask + IFFT448 ----------
// dist-32: v_permlane32_swap. dist-1/2/8: DPP. Only dist 4/16 on LDS pipe.
#define CP 452
__global__ __launch_bounds__(256) void k_colfft(float2* __restrict__ Y1T,
                                                const float* __restrict__ maskP,
                                                const float2* __restrict__ twg) {
    __shared__ float2 ls[4][CP];
    int tid = threadIdx.x;               // 0..255
    int lane = tid & 63, wv = tid >> 6;  // 4 waves
    int oct = blockIdx.x;                // 28
    int byy = blockIdx.y;                // 24 = d + 12*half
    int d = (byy < 12) ? byy : byy - 12;
    int half = (byy < 12) ? 0 : 1;
    int cz = blockIdx.z;
    const float2* w64t = twg + TW_W64;
    const float2* t448 = twg + TW_T448;

    float2* base = Y1T + ((size_t)cz * Dn + d) * (size_t)HWn + (size_t)oct * OCT_F2
                 + 4 * half;             // slots 4*half .. 4*half+3

    // stage in
#pragma unroll
    for (int m = 0; m < 4; ++m) {
        int j4 = tid + m * 256;
        if (j4 < 896) {
            int h = j4 >> 1, q = j4 & 1;
            float4 v = *(const float4*)&base[(size_t)h * 8 + 2 * q];
            ls[2 * q][h]     = make_float2(v.x, v.y);
            ls[2 * q + 1][h] = make_float2(v.z, v.w);
        }
    }
    __syncthreads();

    int L = oct * 8 + 4 * half + wv;     // this wave's line

    float2 xb[7];
#pragma unroll
    for (int b = 0; b < 7; ++b) xb[b] = ls[wv][64 * b + lane];

    float2 tp[7];
#pragma unroll
    for (int d7 = 1; d7 < 7; ++d7) tp[d7] = t448[d7 * 64 + lane];

    // forward DFT7 (Winograd) + W448 twiddle
    float2 y[7];
    dft7<1>(xb, y);
#pragma unroll
    for (int d7 = 1; d7 < 7; ++d7) y[d7] = cmul(y[d7], tp[d7]);

    // ---- forward FFT64, stage dist=32 (permlane-packed pairs) ----
    {
        float2 wst = w64t[lane & 31];
#pragma unroll
        for (int p = 0; p < 3; ++p) {
            float2 u = y[2 * p], v = y[2 * p + 1];
            swap32f(u.x, v.x); swap32f(u.y, v.y);
            y[2 * p]     = cadd(u, v);
            y[2 * p + 1] = cmul(csub(u, v), wst);
        }
        bool hb = lane >= 32;
        float sg = hb ? -1.f : 1.f;
        float2 weff = hb ? wst : make_float2(1.f, 0.f);
        float2 t = shflx2(y[6], 32);
        float2 u6 = make_float2(fmaf(sg, y[6].x, t.x), fmaf(sg, y[6].y, t.y));
        y[6] = cmul(u6, weff);
    }
    // stages dist=16..1
#pragma unroll
    for (int s = 1; s < 6; ++s) {
        int dist = 32 >> s;
        float2 wst = w64t[(lane & (dist - 1)) << s];
        bool hb = (lane & dist) != 0;
        float sg = hb ? -1.f : 1.f;
        float2 weff = hb ? wst : make_float2(1.f, 0.f);
#pragma unroll
        for (int d7 = 0; d7 < 7; ++d7) {
            float2 t = xgroup(y[d7], dist);
            float2 u = make_float2(fmaf(sg, y[d7].x, t.x), fmaf(sg, y[d7].y, t.y));
            y[d7] = cmul(u, weff);
        }
    }

    // mask (packed-adjusted indexing)
    {
        int rb0 = brev5(lane & 31) << 1;
        const float* mbase = maskP + (size_t)L * Hn;
        bool lo = lane < 32;
#pragma unroll
        for (int p = 0; p < 3; ++p) {
            int dsel = lo ? (2 * p) : (2 * p + 1);
            float mS = mbase[7 * rb0 + dsel];
            float mD = mbase[7 * (rb0 + 1) + dsel];
            y[2 * p].x *= mS;     y[2 * p].y *= mS;
            y[2 * p + 1].x *= mD; y[2 * p + 1].y *= mD;
        }
        int rb6 = rb0 | (lane >> 5);
        float m6 = mbase[7 * rb6 + 6];
        y[6].x *= m6; y[6].y *= m6;
    }

    // inverse FFT64, DIT dist=1..16
#pragma unroll
    for (int s = 0; s < 5; ++s) {
        int dist = 1 << s;
        float2 wst = w64t[(lane & (dist - 1)) << (5 - s)];
        wst.y = -wst.y;
        bool hb = (lane & dist) != 0;
        float2 c = hb ? make_float2(-wst.x, -wst.y) : wst;
#pragma unroll
        for (int d7 = 0; d7 < 7; ++d7) {
            float2 t = xgroup(y[d7], dist);
            float2 B = hb ? y[d7] : t;
            float2 A = hb ? t : y[d7];
            y[d7] = cfma(c, B, A);
        }
    }
    // ---- final inverse stage dist=32 ----
    {
        float2 wst = w64t[lane & 31];
        float2 cw  = make_float2(wst.x, -wst.y);
        float2 ncw = make_float2(-cw.x, -cw.y);
#pragma unroll
        for (int p = 0; p < 3; ++p) {
            float2 S = y[2 * p], D = y[2 * p + 1];
            float2 T1 = cfma(cw,  D, S);
            float2 T2 = cfma(ncw, D, S);
            swap32f(T1.x, T2.x); swap32f(T1.y, T2.y);
            y[2 * p] = T1; y[2 * p + 1] = T2;
        }
        bool hb = lane >= 32;
        float2 c = hb ? ncw : cw;
        float2 t = shflx2(y[6], 32);
        float2 B = hb ? y[6] : t;
        float2 A = hb ? t : y[6];
        y[6] = cfma(c, B, A);
    }

    // conj W448 twiddle + inverse DFT7 (Winograd) + LDS writeback
#pragma unroll
    for (int d7 = 1; d7 < 7; ++d7) {
        float2 c = make_float2(tp[d7].x, -tp[d7].y);
        y[d7] = cmul(y[d7], c);
    }
    dft7<-1>(y, xb);
#pragma unroll
    for (int b = 0; b < 7; ++b) ls[wv][64 * b + lane] = xb[b];
    __syncthreads();

    // stage out
#pragma unroll
    for (int m = 0; m < 4; ++m) {
        int j4 = tid + m * 256;
        if (j4 < 896) {
            int h = j4 >> 1, q = j4 & 1;
            float2 a = ls[2 * q][h];
            float2 b = ls[2 * q + 1][h];
            *(float4*)&base[(size_t)h * 8 + 2 * q] = make_float4(a.x, a.y, b.x, b.y);
        }
    }
}

// ---------- fused inverse row FFT + conj-coil + coil-sum + q/dot epilogue ----------
__global__ __launch_bounds__(256) void k_irow_combine(const float2* __restrict__ Y1T,
                                                      const float2* __restrict__ coil,
                                                      const float2* __restrict__ P,
                                                      float2* __restrict__ Qp,
                                                      const float* __restrict__ miu,
                                                      double* __restrict__ S,
                                                      const float2* __restrict__ twg,
                                                      int ccz, int chunkStart,
                                                      int first, int last, int it) {
    __shared__ double sred[8];
    int tid = threadIdx.x;
    int lane = tid & 63, wv = tid >> 6, hi = lane >> 5, l32 = lane & 31;
    int h0 = blockIdx.x * 8, d = blockIdx.y;
    int zid = blockIdx.z;
    int zbase = zid * ccz;
    float2* Q = Qp + (size_t)zid * DHWn;
    int row = h0 + 2 * wv + hi;
    const float2* w32g = twg + TW_W32;
    const float2* t224 = twg + TW_T224;

    float2 tp[7];
#pragma unroll
    for (int d7 = 1; d7 < 7; ++d7) {
        float2 v = t224[d7 * 32 + l32];
        tp[d7] = make_float2(v.x, -v.y);   // conj (inverse twiddle)
    }

    float2 acc[7];
#pragma unroll
    for (int b = 0; b < 7; ++b) acc[b] = make_float2(0.f, 0.f);

    int oct0 = l32 >> 3, l8 = l32 & 7;
    for (int cz = 0; cz < ccz; ++cz) {
        const float2* ybase = Y1T + ((size_t)(zbase + cz) * Dn + d) * (size_t)HWn;
        const float2* crow = coil + (size_t)(chunkStart + zbase + cz) * HWn + (size_t)row * Wn;

        float2 y[7];
#pragma unroll
        for (int d7 = 0; d7 < 7; ++d7)
            y[d7] = ybase[(size_t)(4 * d7 + oct0) * OCT_F2 + (size_t)row * 8 + l8];
        float2 cpre[7];
#pragma unroll
        for (int b = 0; b < 7; ++b) cpre[b] = crow[32 * b + l32];

        // inverse FFT32 across half-wave, DIT (sign-trick)
#pragma unroll
        for (int s = 0; s < 5; ++s) {
            int dist = 1 << s;
            float2 wst = w32g[(l32 & (dist - 1)) << (4 - s)];
            wst.y = -wst.y;
            bool h2 = (l32 & dist) != 0;
            float2 c = h2 ? make_float2(-wst.x, -wst.y) : wst;
#pragma unroll
            for (int d7 = 0; d7 < 7; ++d7) {
                float2 t = xgroup(y[d7], dist);
                float2 B = h2 ? y[d7] : t;
                float2 A = h2 ? t : y[d7];
                y[d7] = cfma(c, B, A);
            }
        }
#pragma unroll
        for (int d7 = 1; d7 < 7; ++d7) y[d7] = cmul(y[d7], tp[d7]);
        float2 s7[7];
        dft7<-1>(y, s7);
#pragma unroll
        for (int b = 0; b < 7; ++b) {
            float2 s = s7[b];
            float2 c = cpre[b];
            acc[b].x += fmaf(s.x, c.x, s.y * c.y);
            acc[b].y += fmaf(s.y, c.x, -s.x * c.y);
        }
    }

    // epilogue: partial q; only zid==0 folds in mu*p (exactly once in the sum).
    float mu = fabsf(miu[0]);
    const float2* prow = P + (size_t)d * HWn + (size_t)row * Wn;
    float2* qrow = Q + (size_t)d * HWn + (size_t)row * Wn;
    double ar = 0.0, ai = 0.0;
#pragma unroll
    for (int b = 0; b < 7; ++b) {
        float2 pv = prow[32 * b + l32];
        float2 s0;
        if (first) {
            if (zid == 0) s0 = make_float2(fmaf(mu, pv.x, acc[b].x), fmaf(mu, pv.y, acc[b].y));
            else          s0 = acc[b];
        } else {
            float2 qv = qrow[32 * b + l32];
            s0 = cadd(qv, acc[b]);
        }
        qrow[32 * b + l32] = s0;
        if (last) {
            ar += (double)(s0.x * pv.x + s0.y * pv.y);
            ai += (double)(s0.y * pv.x - s0.x * pv.y);
        }
    }
    if (last) {
        ar = waveReduce(ar);
        ai = waveReduce(ai);
        if (lane == 0) { sred[wv] = ar; sred[4 + wv] = ai; }
        __syncthreads();
        if (tid == 0) {
            int slot = blockIdx.x & 7;
            atomicAdd(&S[64 + 8 * it + slot],  sred[0] + sred[1] + sred[2] + sred[3]);
            atomicAdd(&S[128 + 8 * it + slot], sred[4] + sred[5] + sred[6] + sred[7]);
        }
    }
}

// ---------- CG scalar update (float4 = 2 complex per lane) ----------
// Per-block LDS reduction -> one slot-spread atomic per block.
__global__ void k_update_br(const double* __restrict__ Sin, double* __restrict__ S, int it,
                            const float4* __restrict__ p, const float4* __restrict__ q,
                            int nz,
                            float4* __restrict__ b, float4* __restrict__ r) {
    __shared__ double sred[4];
    double rr = sum8(Sin + 8 * it);
    double qr = sum8(Sin + 64 + 8 * it);
    double qi = sum8(Sin + 128 + 8 * it);
    double den = qr * qr + qi * qi;
    float arf = (float)(rr * qr / den);
    float aif = (float)(-rr * qi / den);
    double acc = 0.0;
    const int N2 = DHWn / 2;
    for (int e = blockIdx.x * blockDim.x + threadIdx.x; e < N2; e += gridDim.x * blockDim.x) {
        float4 pv = p[e], bv = b[e], rv = r[e];
        float4 qv = q[e];
        for (int z = 1; z < nz; ++z) {
            float4 t = q[(size_t)z * N2 + e];
            qv.x += t.x; qv.y += t.y; qv.z += t.z; qv.w += t.w;
        }
        bv.x += arf * pv.x - aif * pv.y;  bv.y += arf * pv.y + aif * pv.x;
        bv.z += arf * pv.z - aif * pv.w;  bv.w += arf * pv.w + aif * pv.z;
        b[e] = bv;
        rv.x -= arf * qv.x - aif * qv.y;  rv.y -= arf * qv.y + aif * qv.x;
        rv.z -= arf * qv.z - aif * qv.w;  rv.w -= arf * qv.w + aif * qv.z;
        r[e] = rv;
        acc += (double)rv.x * rv.x + (double)rv.y * rv.y
             + (double)rv.z * rv.z + (double)rv.w * rv.w;
    }
    acc = waveReduce(acc);
    if ((threadIdx.x & 63) == 0) sred[threadIdx.x >> 6] = acc;
    __syncthreads();
    if (threadIdx.x == 0)
        atomicAdd(&S[8 * (it + 1) + (blockIdx.x & 7)],
                  (sred[0] + sred[1]) + (sred[2] + sred[3]));
}

// float4-vectorized output (shift-aligned quads)
__global__ void k_output(const float2* __restrict__ b, float* __restrict__ out) {
    const int N4 = DHWn / 4;
    int e4 = blockIdx.x * blockDim.x + threadIdx.x;
    if (e4 >= N4) return;
    int e = 4 * e4;
    int d = e / HWn, rem = e - d * HWn;
    int h = rem / Wn, w = rem - h * Wn;
    int hs = h + Hn / 2; if (hs >= Hn) hs -= Hn;
    int ws = w + Wn / 2; if (ws >= Wn) ws -= Wn;
    int src = d * HWn + hs * Wn + ws;                  // src % 4 == 0
    float4 a  = ((const float4*)b)[src / 2];
    float4 bb = ((const float4*)b)[src / 2 + 1];
    *(float4*)&out[e]        = make_float4(a.x, a.z, bb.x, bb.z);
    *(float4*)&out[DHWn + e] = make_float4(a.y, a.w, bb.y, bb.w);
}

extern "C" void kernel_launch(void* const* d_in, const int* in_sizes, int n_in,
                              void* d_out, int out_size, void* d_ws, size_t ws_size,
                              hipStream_t stream) {
    const float* z      = (const float*)d_in[0];
    const float* zf     = (const float*)d_in[1];
    const float* coil_r = (const float*)d_in[2];
    const float* coil_i = (const float*)d_in[3];
    const int*   maskp  = (const int*)d_in[4];
    const float* miu    = (const float*)d_in[5];
    float* out = (float*)d_out;

    char* w = (char*)d_ws;
    size_t off = 0;
    auto carve = [&](size_t bytes) -> void* {
        void* ptr = w + off;
        off += (bytes + 511) & ~(size_t)511;
        return ptr;
    };
    float2* P0    = (float2*)carve((size_t)DHWn * 8);
    float2* P1    = (float2*)carve((size_t)DHWn * 8);
    float2* R     = (float2*)carve((size_t)DHWn * 8);
    float2* Bv    = (float2*)carve((size_t)DHWn * 8);
    float2* COIL  = (float2*)carve((size_t)Cn * HWn * 8);
    float*  MASKP = (float*)carve((size_t)HWn * 4);
    float2* TWS   = (float2*)carve(TW_NT * 8);
    double* S     = (double*)carve(S_NDBL * 8);

    size_t imgSet = (size_t)DHWn * 8;   // one coil-slot (12 slices), 9.63 MB
    int cc = 1, NZ = 1;
    {
        const int cand[6][2] = {{10,2},{10,1},{5,1},{2,1},{1,1},{1,1}};
        for (int i = 0; i < 6; ++i) {
            size_t need = off + (size_t)(cand[i][0] + cand[i][1]) * imgSet;
            if (need <= ws_size) { cc = cand[i][0]; NZ = cand[i][1]; break; }
        }
    }
    float2* Qp  = (float2*)carve((size_t)NZ * imgSet);   // NZ partial-q buffers
    float2* Y1T = (float2*)carve((size_t)cc * imgSet);   // staged slices [c][d][oct][h][l8]
    int nch = Cn / cc;
    int ccz = cc / NZ;

    k_init_misc<<<1, 1024, 0, stream>>>(TWS, S);
    k_build_p<<<(DHWn / 4 + 255) / 256, 256, 0, stream>>>(z, zf, miu, P0, R, Bv, S);
    k_build_coil<<<(Cn * HWn / 4 + 255) / 256, 256, 0, stream>>>(coil_r, coil_i, COIL);
    k_build_mask<<<512, 256, 0, stream>>>(maskp, MASKP);

    for (int it = 0; it < 5; ++it) {
        float2* Pcur = (it & 1) ? P1 : P0;     // p for this iteration
        float2* Pold = (it & 1) ? P0 : P1;     // previous p (read source for it>=1)
        const float2* Pread = (it == 0) ? Pcur : Pold;
        for (int ch = 0; ch < nch; ++ch) {
            int cs = ch * cc;
            dim3 gf(Hn / 8, Dn, cc);    // 56 x 12 x cc
            dim3 gc(28, 24, cc);        // octet x (d + 12*half) x cc
            dim3 gi(Hn / 8, Dn, NZ);    // 56 x 12 x NZ, each z does cc/NZ coils
            k_rowfft0<<<gf, 256, 0, stream>>>(Pread, R, Pcur, COIL, Y1T, TWS, S, cs, it);
            k_colfft<<<gc, 256, 0, stream>>>(Y1T, MASKP, TWS);
            k_irow_combine<<<gi, 256, 0, stream>>>(Y1T, COIL, Pcur, Qp, miu, S, TWS,
                                                   ccz, cs, ch == 0 ? 1 : 0,
                                                   ch == nch - 1 ? 1 : 0, it);
        }
        k_update_br<<<1024, 256, 0, stream>>>(S, S, it, (const float4*)Pcur, (const float4*)Qp,
                                              NZ, (float4*)Bv, (float4*)R);
    }
    k_output<<<(DHWn / 4 + 255) / 256, 256, 0, stream>>>(Bv, out);
}